// Round 9
// baseline (410.914 us; speedup 1.0000x reference)
//
#include <hip/hip_runtime.h>

// AttackLSTM R24 — clean v_pk_fma_f16 rate test on the R23 self-timed skeleton.
// R23 post-mortem: de-barriering bought 3% -> stage-throughput-bound,
// 1610cy/step. Across R16-R23, VALUBusy*step = 1100-1200 issue-cy/SIMD/step
// vs ~600 static @2cy/fdot2. ONE hypothesis explains the 2x in all rounds:
// v_dot2_f32_f16 is ~4cy (half rate). R18's pk_fma null was confounded
// (AGPR-parked weights -> accvgpr_read dominated both variants). R23's
// structure (VGPR=104, no parking) is the first clean testbed.
// R24 = R23 with: (1) rec/proj dots as v_pk_fma_f16, paired v2h accums
// (R18 numerics, passed), combine via 2 fdot2-with-ones per gate;
// (2) s_sleep(1) in spin-waits (stop light waves polluting rec SIMDs).
// Predict: full-rate pk_fma -> rec dot issue 512->256cy, dur ~240-270us.
// Null -> multi-resource saturation; structure near floor.
// Edges: w0(a0)->w4,w5(a1proj)->w1(a1rec)->w6,w7(a2proj)->w2(a2rec)->w3(b).
// CH=8, NS=16, 64 windows.

#define BB 256
#define TT 512
#define CH 8
#define NS 16  // ring slots = 2*CH
#define NW (TT / CH)

typedef _Float16 v2h __attribute__((ext_vector_type(2)));

__device__ __forceinline__ float sig_(float x) {
  return __builtin_amdgcn_rcpf(1.f + __builtin_amdgcn_exp2f(-1.44269504f * x));
}
__device__ __forceinline__ float tanh_(float x) {
  return __builtin_fmaf(2.f, __builtin_amdgcn_rcpf(1.f + __builtin_amdgcn_exp2f(-2.88539008f * x)), -1.f);
}

template <int K>
__device__ __forceinline__ float qb_(float v) {
  return __int_as_float(__builtin_amdgcn_update_dpp(
      0, __float_as_int(v), (K | (K << 2) | (K << 4) | (K << 6)), 0xF, 0xF, true));
}

#if __has_builtin(__builtin_amdgcn_fdot2)
#define FDOT2(acc, a, b) (acc) = __builtin_amdgcn_fdot2((a), (b), (acc), false)
#else
#define FDOT2(acc, a, b) \
  (acc) = __builtin_fmaf((float)(a)[0], (float)(b)[0], \
          __builtin_fmaf((float)(a)[1], (float)(b)[1], (acc)))
#endif

#if __has_builtin(__builtin_elementwise_fma)
#define PKFMA(acc, a, b) (acc) = __builtin_elementwise_fma((a), (b), (acc))
#else
#define PKFMA(acc, a, b) (acc) += (a) * (b)
#endif

#define KEEPP(a) asm volatile("" : "+v"(a))
#define PIN16(w)                                                            \
  do {                                                                      \
    _Pragma("unroll") for (int _i = 0; _i < 16; ++_i) KEEPP((w)[_i]);       \
  } while (0)

// Spin until prog[i] >= v (acquire), sleeping between polls.
#define WAITP(i, v)                                                           \
  while (__hip_atomic_load(&prog[i], __ATOMIC_ACQUIRE,                        \
                           __HIP_MEMORY_SCOPE_WORKGROUP) < (v)) {             \
    __builtin_amdgcn_s_sleep(1);                                              \
  }
// Publish prog[i] = v after all this wave's data ds_writes retired.
#define POSTP(i, v)                                                           \
  do {                                                                        \
    asm volatile("s_waitcnt lgkmcnt(0)" ::: "memory");                        \
    if (lane == 0)                                                            \
      __hip_atomic_store(&prog[i], (v), __ATOMIC_RELEASE,                     \
                         __HIP_MEMORY_SCOPE_WORKGROUP);                       \
  } while (0)

__device__ __forceinline__ v2h bc2h_(int v) { return __builtin_bit_cast(v2h, v); }
__device__ __forceinline__ int pk2_(float x, float y) {
  return __builtin_bit_cast(int, v2h{(_Float16)x, (_Float16)y});
}

// 64 halfs from LDS as 32 v2h via int4 reads (8x ds_read_b128).
__device__ __forceinline__ void load_h64(const _Float16* p, v2h hv[32]) {
  const int4* hp = reinterpret_cast<const int4*>(p);
#pragma unroll
  for (int i = 0; i < 8; ++i) {
    int4 blk = hp[i];
    hv[4 * i + 0] = bc2h_(blk.x);
    hv[4 * i + 1] = bc2h_(blk.y);
    hv[4 * i + 2] = bc2h_(blk.z);
    hv[4 * i + 3] = bc2h_(blk.w);
  }
}

// fp32 row of 64 -> two 16-v2h halves (k 0..31 -> lo, k 32..63 -> hi).
__device__ __forceinline__ void load_row_pair(const float* src, v2h lo[16], v2h hi[16]) {
  const float4* p = reinterpret_cast<const float4*>(src);
#pragma unroll
  for (int i = 0; i < 8; ++i) {
    float4 v = p[i];
    lo[2 * i]     = v2h{(_Float16)v.x, (_Float16)v.y};
    lo[2 * i + 1] = v2h{(_Float16)v.z, (_Float16)v.w};
  }
#pragma unroll
  for (int i = 0; i < 8; ++i) {
    float4 v = p[8 + i];
    hi[2 * i]     = v2h{(_Float16)v.x, (_Float16)v.y};
    hi[2 * i + 1] = v2h{(_Float16)v.z, (_Float16)v.w};
  }
}

// Rec-wave weight preload: K 0..31 of rows q*64+lane into arch regs wt[q],
// K 32..63 converted and written to the LDS weight mirror (80B row pitch).
__device__ __forceinline__ void load_rec_w(const float* W, int lane,
                                           v2h wt[4][16], unsigned char* wl) {
#pragma unroll
  for (int q = 0; q < 4; ++q) {
    const int row = q * 64 + lane;
    const float4* p = reinterpret_cast<const float4*>(W + row * 64);
#pragma unroll
    for (int i = 0; i < 8; ++i) {
      float4 v = p[i];
      wt[q][2 * i]     = v2h{(_Float16)v.x, (_Float16)v.y};
      wt[q][2 * i + 1] = v2h{(_Float16)v.z, (_Float16)v.w};
    }
#pragma unroll
    for (int i = 0; i < 4; ++i) {
      float4 va = p[8 + 2 * i], vb = p[9 + 2 * i];
      int4 blk;
      blk.x = pk2_(va.x, va.y); blk.y = pk2_(va.z, va.w);
      blk.z = pk2_(vb.x, vb.y); blk.w = pk2_(vb.z, vb.w);
      *reinterpret_cast<int4*>(wl + row * 80 + i * 16) = blk;
    }
  }
}

// Full 4-gate dot via v_pk_fma_f16: arch half (wt, k 0..31) + LDS-streamed
// half (k 32..63). Paired v2h accumulators; combine via fdot2 with ones.
// p holds init value (bias).
__device__ __forceinline__ void dot4full_(const v2h wt[4][16],
                                          const unsigned char* wl, int lane,
                                          const v2h hv[32],
                                          float& p0, float& p1, float& p2, float& p3) {
  v2h A0{}, A1{}, A2{}, A3{}, B0{}, B1{}, B2{}, B3{};
#pragma unroll
  for (int j = 0; j < 16; j += 2) {
    PKFMA(A0, wt[0][j], hv[j]);         PKFMA(A1, wt[1][j], hv[j]);
    PKFMA(A2, wt[2][j], hv[j]);         PKFMA(A3, wt[3][j], hv[j]);
    PKFMA(B0, wt[0][j + 1], hv[j + 1]); PKFMA(B1, wt[1][j + 1], hv[j + 1]);
    PKFMA(B2, wt[2][j + 1], hv[j + 1]); PKFMA(B3, wt[3][j + 1], hv[j + 1]);
  }
  const int rb0 = lane * 80, rb1 = (64 + lane) * 80,
            rb2 = (128 + lane) * 80, rb3 = (192 + lane) * 80;
#pragma unroll
  for (int jb = 0; jb < 4; ++jb) {
    int4 w0 = *reinterpret_cast<const int4*>(wl + rb0 + jb * 16);
    int4 w1 = *reinterpret_cast<const int4*>(wl + rb1 + jb * 16);
    int4 w2 = *reinterpret_cast<const int4*>(wl + rb2 + jb * 16);
    int4 w3 = *reinterpret_cast<const int4*>(wl + rb3 + jb * 16);
    const int h0 = 16 + jb * 4;
    PKFMA(A0, bc2h_(w0.x), hv[h0 + 0]); PKFMA(B0, bc2h_(w0.y), hv[h0 + 1]);
    PKFMA(A0, bc2h_(w0.z), hv[h0 + 2]); PKFMA(B0, bc2h_(w0.w), hv[h0 + 3]);
    PKFMA(A1, bc2h_(w1.x), hv[h0 + 0]); PKFMA(B1, bc2h_(w1.y), hv[h0 + 1]);
    PKFMA(A1, bc2h_(w1.z), hv[h0 + 2]); PKFMA(B1, bc2h_(w1.w), hv[h0 + 3]);
    PKFMA(A2, bc2h_(w2.x), hv[h0 + 0]); PKFMA(B2, bc2h_(w2.y), hv[h0 + 1]);
    PKFMA(A2, bc2h_(w2.z), hv[h0 + 2]); PKFMA(B2, bc2h_(w2.w), hv[h0 + 3]);
    PKFMA(A3, bc2h_(w3.x), hv[h0 + 0]); PKFMA(B3, bc2h_(w3.y), hv[h0 + 1]);
    PKFMA(A3, bc2h_(w3.z), hv[h0 + 2]); PKFMA(B3, bc2h_(w3.w), hv[h0 + 3]);
  }
  const v2h one = {(_Float16)1.f, (_Float16)1.f};
  FDOT2(p0, A0, one); FDOT2(p1, A1, one); FDOT2(p2, A2, one); FDOT2(p3, A3, one);
  FDOT2(p0, B0, one); FDOT2(p1, B1, one); FDOT2(p2, B2, one); FDOT2(p3, B3, one);
}

// 2-gate proj dot over full k via v_pk_fma_f16.
__device__ __forceinline__ void dot2g_(const v2h* wa_lo, const v2h* wa_hi,
                                       const v2h* wb_lo, const v2h* wb_hi,
                                       const v2h hv[32], float& p0, float& p1) {
  v2h A0{}, A1{}, B0{}, B1{};
#pragma unroll
  for (int j = 0; j < 16; j += 2) {
    PKFMA(A0, wa_lo[j], hv[j]);          PKFMA(B0, wa_lo[j + 1], hv[j + 1]);
    PKFMA(A0, wa_hi[j], hv[16 + j]);     PKFMA(B0, wa_hi[j + 1], hv[17 + j]);
    PKFMA(A1, wb_lo[j], hv[j]);          PKFMA(B1, wb_lo[j + 1], hv[j + 1]);
    PKFMA(A1, wb_hi[j], hv[16 + j]);     PKFMA(B1, wb_hi[j + 1], hv[17 + j]);
  }
  const v2h one = {(_Float16)1.f, (_Float16)1.f};
  float r0 = 0.f, r1 = 0.f;
  FDOT2(r0, A0, one); FDOT2(r1, A1, one);
  FDOT2(r0, B0, one); FDOT2(r1, B1, one);
  p0 = r0; p1 = r1;
}

__global__ __attribute__((amdgpu_flat_work_group_size(512, 512),
                          amdgpu_waves_per_eu(2, 2)))
void lstm_pipe_k(
    const float* __restrict__ x,
    const float* __restrict__ wih_a0, const float* __restrict__ whh_a0,
    const float* __restrict__ bih_a0, const float* __restrict__ bhh_a0,
    const float* __restrict__ wih_a1, const float* __restrict__ whh_a1,
    const float* __restrict__ bih_a1, const float* __restrict__ bhh_a1,
    const float* __restrict__ wih_a2, const float* __restrict__ whh_a2,
    const float* __restrict__ bih_a2, const float* __restrict__ bhh_a2,
    const float* __restrict__ wih_b0, const float* __restrict__ whh_b0,
    const float* __restrict__ bih_b0, const float* __restrict__ bhh_b0,
    const float* __restrict__ wih_b1, const float* __restrict__ whh_b1,
    const float* __restrict__ bih_b1, const float* __restrict__ bhh_b1,
    const float* __restrict__ wih_b2, const float* __restrict__ whh_b2,
    const float* __restrict__ bih_b2, const float* __restrict__ bhh_b2,
    float* __restrict__ out)  // [B,T]
{
  const int b = blockIdx.x;
  const int tid = threadIdx.x;
  const int wave = tid >> 6;
  const int lane = tid & 63;

  __shared__ __align__(16) _Float16 hh[3][NS][64];          // h rings
  __shared__ __align__(16) float pj[2][NS][256];            // proj rings
  __shared__ __align__(16) unsigned char wlds[3][256 * 80]; // streamed W halves
  __shared__ float xs[TT];
  __shared__ int prog[8];                                   // per-wave windows done

  for (int i = tid; i < TT; i += 512) xs[i] = x[(size_t)b * TT + i];
  for (int i = tid; i < 3 * NS * 64 / 2; i += 512) reinterpret_cast<int*>(hh)[i] = 0;
  if (tid < 8) prog[tid] = 0;

  v2h wt[4][16];
  float bias[4] = {0.f, 0.f, 0.f, 0.f};
  float wi0_[4] = {0.f, 0.f, 0.f, 0.f};
  float whb0[4] = {}, wi1b[4] = {}, wh1b[4] = {}, bb1[4] = {},
        wi2b[4] = {}, wh2b[4] = {}, bb2[4] = {};

  if (wave == 0) {  // a0 recurrence
    load_rec_w(whh_a0, lane, wt, &wlds[0][0]);
#pragma unroll
    for (int q = 0; q < 4; ++q) {
      const int row = q * 64 + lane;
      bias[q] = bih_a0[row] + bhh_a0[row];
      wi0_[q] = wih_a0[row];
    }
    PIN16(wt[0]); PIN16(wt[1]); PIN16(wt[2]); PIN16(wt[3]);
  } else if (wave == 1) {  // a1 recurrence
    load_rec_w(whh_a1, lane, wt, &wlds[1][0]);
#pragma unroll
    for (int q = 0; q < 4; ++q) bias[q] = bih_a1[q * 64 + lane] + bhh_a1[q * 64 + lane];
    PIN16(wt[0]); PIN16(wt[1]); PIN16(wt[2]); PIN16(wt[3]);
  } else if (wave == 2) {  // a2 recurrence
    load_rec_w(whh_a2, lane, wt, &wlds[2][0]);
#pragma unroll
    for (int q = 0; q < 4; ++q) bias[q] = bih_a2[q * 64 + lane] + bhh_a2[q * 64 + lane];
    PIN16(wt[0]); PIN16(wt[1]); PIN16(wt[2]); PIN16(wt[3]);
  } else if (wave == 3) {  // b-chain: one row of wih_b0 in wt[0](lo)/wt[1](hi)
    const int q = lane & 3;
    load_row_pair(wih_b0 + q * 64, wt[0], wt[1]);
    bias[0] = bih_b0[q] + bhh_b0[q];
#pragma unroll
    for (int k = 0; k < 4; ++k) {
      whb0[k] = whh_b0[k];
      wi1b[k] = wih_b1[k]; wh1b[k] = whh_b1[k]; bb1[k] = bih_b1[k] + bhh_b1[k];
      wi2b[k] = wih_b2[k]; wh2b[k] = whh_b2[k]; bb2[k] = bih_b2[k] + bhh_b2[k];
    }
    PIN16(wt[0]); PIN16(wt[1]);
  } else if (wave == 4) {  // a1 proj gates 0,1
    load_row_pair(wih_a1 + (0 * 64 + lane) * 64, wt[0], wt[1]);
    load_row_pair(wih_a1 + (1 * 64 + lane) * 64, wt[2], wt[3]);
    PIN16(wt[0]); PIN16(wt[1]); PIN16(wt[2]); PIN16(wt[3]);
  } else if (wave == 5) {  // a1 proj gates 2,3
    load_row_pair(wih_a1 + (2 * 64 + lane) * 64, wt[0], wt[1]);
    load_row_pair(wih_a1 + (3 * 64 + lane) * 64, wt[2], wt[3]);
    PIN16(wt[0]); PIN16(wt[1]); PIN16(wt[2]); PIN16(wt[3]);
  } else if (wave == 6) {  // a2 proj gates 0,1
    load_row_pair(wih_a2 + (0 * 64 + lane) * 64, wt[0], wt[1]);
    load_row_pair(wih_a2 + (1 * 64 + lane) * 64, wt[2], wt[3]);
    PIN16(wt[0]); PIN16(wt[1]); PIN16(wt[2]); PIN16(wt[3]);
  } else {                 // a2 proj gates 2,3
    load_row_pair(wih_a2 + (2 * 64 + lane) * 64, wt[0], wt[1]);
    load_row_pair(wih_a2 + (3 * 64 + lane) * 64, wt[2], wt[3]);
    PIN16(wt[0]); PIN16(wt[1]); PIN16(wt[2]); PIN16(wt[3]);
  }
  __syncthreads();

  float c = 0.f;
  float h0b = 0.f, c0b = 0.f, h1b = 0.f, c1b = 0.f, h2b = 0.f, c2b = 0.f;

  if (wave == 0) {  // a0 rec -> hh[0]; ring consumers w4,w5
    __builtin_amdgcn_s_setprio(1);
    for (int k = 0; k < NW; ++k) {
      if (k >= 2) { WAITP(4, k - 1); WAITP(5, k - 1); }
      const int t0 = k * CH;
      for (int s = 0; s < CH; ++s) {
        const int t = t0 + s;
        v2h hv[32];
        load_h64(&hh[0][(t + NS - 1) & (NS - 1)][0], hv);
        const float xv = xs[t];
        float p0 = bias[0], p1 = bias[1], p2 = bias[2], p3 = bias[3];
        dot4full_(wt, &wlds[0][0], lane, hv, p0, p1, p2, p3);
        p0 = __builtin_fmaf(wi0_[0], xv, p0);
        p1 = __builtin_fmaf(wi0_[1], xv, p1);
        p2 = __builtin_fmaf(wi0_[2], xv, p2);
        p3 = __builtin_fmaf(wi0_[3], xv, p3);
        float gi = sig_(p0), gf = sig_(p1), gg = tanh_(p2), go = sig_(p3);
        c = __builtin_fmaf(gf, c, gi * gg);
        hh[0][t & (NS - 1)][lane] = (_Float16)(go * tanh_(c));
      }
      POSTP(0, k + 1);
    }
    __builtin_amdgcn_s_setprio(0);
  } else if (wave == 1) {  // a1 rec: reads pj[0]; -> hh[1]; ring consumers w6,w7
    __builtin_amdgcn_s_setprio(1);
    for (int k = 0; k < NW; ++k) {
      WAITP(4, k + 1); WAITP(5, k + 1);
      if (k >= 2) { WAITP(6, k - 1); WAITP(7, k - 1); }
      const int t0 = k * CH;
      for (int s = 0; s < CH; ++s) {
        const int t = t0 + s;
        v2h hv[32];
        load_h64(&hh[1][(t + NS - 1) & (NS - 1)][0], hv);
        float4 pr = *reinterpret_cast<const float4*>(&pj[0][t & (NS - 1)][lane * 4]);
        float p0 = bias[0], p1 = bias[1], p2 = bias[2], p3 = bias[3];
        dot4full_(wt, &wlds[1][0], lane, hv, p0, p1, p2, p3);
        p0 += pr.x; p1 += pr.y; p2 += pr.z; p3 += pr.w;
        float gi = sig_(p0), gf = sig_(p1), gg = tanh_(p2), go = sig_(p3);
        c = __builtin_fmaf(gf, c, gi * gg);
        hh[1][t & (NS - 1)][lane] = (_Float16)(go * tanh_(c));
      }
      POSTP(1, k + 1);
    }
    __builtin_amdgcn_s_setprio(0);
  } else if (wave == 2) {  // a2 rec: reads pj[1]; -> hh[2]; ring consumer w3
    __builtin_amdgcn_s_setprio(1);
    for (int k = 0; k < NW; ++k) {
      WAITP(6, k + 1); WAITP(7, k + 1);
      if (k >= 2) { WAITP(3, k - 1); }
      const int t0 = k * CH;
      for (int s = 0; s < CH; ++s) {
        const int t = t0 + s;
        v2h hv[32];
        load_h64(&hh[2][(t + NS - 1) & (NS - 1)][0], hv);
        float4 pr = *reinterpret_cast<const float4*>(&pj[1][t & (NS - 1)][lane * 4]);
        float p0 = bias[0], p1 = bias[1], p2 = bias[2], p3 = bias[3];
        dot4full_(wt, &wlds[2][0], lane, hv, p0, p1, p2, p3);
        p0 += pr.x; p1 += pr.y; p2 += pr.z; p3 += pr.w;
        float gi = sig_(p0), gf = sig_(p1), gg = tanh_(p2), go = sig_(p3);
        c = __builtin_fmaf(gf, c, gi * gg);
        hh[2][t & (NS - 1)][lane] = (_Float16)(go * tanh_(c));
      }
      POSTP(2, k + 1);
    }
    __builtin_amdgcn_s_setprio(0);
  } else if (wave == 3) {  // b-chain: reads hh[2]
    for (int k = 0; k < NW; ++k) {
      WAITP(2, k + 1);
      const int t0 = k * CH;
      for (int s = 0; s < CH; ++s) {
        const int t = t0 + s;
        v2h hv[32];
        load_h64(&hh[2][t & (NS - 1)][0], hv);
        float pga = bias[0], pgb = 0.f;
#pragma unroll
        for (int j = 0; j < 16; ++j) {
          FDOT2(pga, wt[0][j], hv[j]);
          FDOT2(pgb, wt[1][j], hv[16 + j]);
        }
        float pg = pga + pgb;
        float p_i = qb_<0>(pg), p_f = qb_<1>(pg), p_g = qb_<2>(pg), p_o = qb_<3>(pg);
        float i0 = sig_(__builtin_fmaf(whb0[0], h0b, p_i));
        float f0 = sig_(__builtin_fmaf(whb0[1], h0b, p_f));
        float g0 = tanh_(__builtin_fmaf(whb0[2], h0b, p_g));
        float o0 = sig_(__builtin_fmaf(whb0[3], h0b, p_o));
        c0b = __builtin_fmaf(f0, c0b, i0 * g0);
        h0b = o0 * tanh_(c0b);
        float i1 = sig_(bb1[0] + __builtin_fmaf(wi1b[0], h0b, wh1b[0] * h1b));
        float f1 = sig_(bb1[1] + __builtin_fmaf(wi1b[1], h0b, wh1b[1] * h1b));
        float g1 = tanh_(bb1[2] + __builtin_fmaf(wi1b[2], h0b, wh1b[2] * h1b));
        float o1 = sig_(bb1[3] + __builtin_fmaf(wi1b[3], h0b, wh1b[3] * h1b));
        c1b = __builtin_fmaf(f1, c1b, i1 * g1);
        h1b = o1 * tanh_(c1b);
        float i2 = sig_(bb2[0] + __builtin_fmaf(wi2b[0], h1b, wh2b[0] * h2b));
        float f2 = sig_(bb2[1] + __builtin_fmaf(wi2b[1], h1b, wh2b[1] * h2b));
        float g2 = tanh_(bb2[2] + __builtin_fmaf(wi2b[2], h1b, wh2b[2] * h2b));
        float o2 = sig_(bb2[3] + __builtin_fmaf(wi2b[3], h1b, wh2b[3] * h2b));
        c2b = __builtin_fmaf(f2, c2b, i2 * g2);
        h2b = o2 * tanh_(c2b);
        if (lane == 0) out[(size_t)b * TT + t] = h2b;
      }
      POSTP(3, k + 1);
    }
  } else if (wave == 4) {  // a1 proj g01: reads hh[0]; -> pj[0].xy; consumer w1
    for (int k = 0; k < NW; ++k) {
      WAITP(0, k + 1);
      if (k >= 2) { WAITP(1, k - 1); }
      const int t0 = k * CH;
      for (int s = 0; s < CH; ++s) {
        const int t = t0 + s;
        v2h hv[32];
        load_h64(&hh[0][t & (NS - 1)][0], hv);
        float p0, p1;
        dot2g_(wt[0], wt[1], wt[2], wt[3], hv, p0, p1);
        *reinterpret_cast<float2*>(&pj[0][t & (NS - 1)][lane * 4]) = float2{p0, p1};
      }
      POSTP(4, k + 1);
    }
  } else if (wave == 5) {  // a1 proj g23
    for (int k = 0; k < NW; ++k) {
      WAITP(0, k + 1);
      if (k >= 2) { WAITP(1, k - 1); }
      const int t0 = k * CH;
      for (int s = 0; s < CH; ++s) {
        const int t = t0 + s;
        v2h hv[32];
        load_h64(&hh[0][t & (NS - 1)][0], hv);
        float p2, p3;
        dot2g_(wt[0], wt[1], wt[2], wt[3], hv, p2, p3);
        *reinterpret_cast<float2*>(&pj[0][t & (NS - 1)][lane * 4 + 2]) = float2{p2, p3};
      }
      POSTP(5, k + 1);
    }
  } else if (wave == 6) {  // a2 proj g01: reads hh[1]; -> pj[1].xy; consumer w2
    for (int k = 0; k < NW; ++k) {
      WAITP(1, k + 1);
      if (k >= 2) { WAITP(2, k - 1); }
      const int t0 = k * CH;
      for (int s = 0; s < CH; ++s) {
        const int t = t0 + s;
        v2h hv[32];
        load_h64(&hh[1][t & (NS - 1)][0], hv);
        float p0, p1;
        dot2g_(wt[0], wt[1], wt[2], wt[3], hv, p0, p1);
        *reinterpret_cast<float2*>(&pj[1][t & (NS - 1)][lane * 4]) = float2{p0, p1};
      }
      POSTP(6, k + 1);
    }
  } else {                 // a2 proj g23
    for (int k = 0; k < NW; ++k) {
      WAITP(1, k + 1);
      if (k >= 2) { WAITP(2, k - 1); }
      const int t0 = k * CH;
      for (int s = 0; s < CH; ++s) {
        const int t = t0 + s;
        v2h hv[32];
        load_h64(&hh[1][t & (NS - 1)][0], hv);
        float p2, p3;
        dot2g_(wt[0], wt[1], wt[2], wt[3], hv, p2, p3);
        *reinterpret_cast<float2*>(&pj[1][t & (NS - 1)][lane * 4 + 2]) = float2{p2, p3};
      }
      POSTP(7, k + 1);
    }
  }
}

extern "C" void kernel_launch(void* const* d_in, const int* in_sizes, int n_in,
                              void* d_out, int out_size, void* d_ws, size_t ws_size,
                              hipStream_t stream) {
  const float* x      = (const float*)d_in[0];
  const float* wih_a0 = (const float*)d_in[1];
  const float* whh_a0 = (const float*)d_in[2];
  const float* bih_a0 = (const float*)d_in[3];
  const float* bhh_a0 = (const float*)d_in[4];
  const float* wih_a1 = (const float*)d_in[5];
  const float* whh_a1 = (const float*)d_in[6];
  const float* bih_a1 = (const float*)d_in[7];
  const float* bhh_a1 = (const float*)d_in[8];
  const float* wih_a2 = (const float*)d_in[9];
  const float* whh_a2 = (const float*)d_in[10];
  const float* bih_a2 = (const float*)d_in[11];
  const float* bhh_a2 = (const float*)d_in[12];
  const float* wih_b0 = (const float*)d_in[13];
  const float* whh_b0 = (const float*)d_in[14];
  const float* bih_b0 = (const float*)d_in[15];
  const float* bhh_b0 = (const float*)d_in[16];
  const float* wih_b1 = (const float*)d_in[17];
  const float* whh_b1 = (const float*)d_in[18];
  const float* bih_b1 = (const float*)d_in[19];
  const float* bhh_b1 = (const float*)d_in[20];
  const float* wih_b2 = (const float*)d_in[21];
  const float* whh_b2 = (const float*)d_in[22];
  const float* bih_b2 = (const float*)d_in[23];
  const float* bhh_b2 = (const float*)d_in[24];
  float* out = (float*)d_out;

  lstm_pipe_k<<<BB, 512, 0, stream>>>(
      x,
      wih_a0, whh_a0, bih_a0, bhh_a0,
      wih_a1, whh_a1, bih_a1, bhh_a1,
      wih_a2, whh_a2, bih_a2, bhh_a2,
      wih_b0, whh_b0, bih_b0, bhh_b0,
      wih_b1, whh_b1, bih_b1, bhh_b1,
      wih_b2, whh_b2, bih_b2, bhh_b2,
      out);
}

// Round 10
// 389.106 us; speedup vs baseline: 1.0560x; 1.0560x over previous
//
#include <hip/hip_runtime.h>

// AttackLSTM R25 — LDS-pipe starvation + MFMA proj offload, 6-wave self-timed.
// R24 post-mortem: pk_fma==fdot2 (clean null). Re-derivation: wlds streaming
// = 48 full-fat ds_read_b128/step (16B/lane); with b128~12cy (m134) the LDS
// data pipe was ~85-90% of the 1610cy step -> THE invariant binding resource
// across R16-R24. Plus rec SIMDs shared with VALU-heavy proj waves.
// R25: (1) rec weights fully register-resident (R17 wt[4][32], AGPR-parked
// overflow + copy tax — VALU has headroom now) -> wlds gone. (2) proj on
// the MATRIX pipe: w4/w5 hold W as AGPR A-fragments (R21-validated
// ldbfrag_), B = h over 8 timestep-cols (4 ds_read_b64/window), 16 tiles x
// 2 MFMA per window; proj VALU ~20cy/step -> rec waves own their SIMDs.
// (3) 6 waves/384thr: w0-2 rec S0-2, w3 b-chain sole S3, w4/w5 partner S0/S1.
// Self-timed prog[6]: w0->w4->w1->w5->w2->w3, back-pressure k-1 edges.
// D layout: col=lane&15=timestep (R21-validated), row=(lane>>4)*4+reg (m89).
// MFMA under FULL exec (A rows live in lanes c>=8); only writes masked c<8.
// Cols 8-15 compute garbage from the other ring half — provably unused.
// Verify: WRITE_SIZE ~512KB (no spill), MfmaUtil>0, absmax pass.

#define BB 256
#define TT 512
#define CH 8
#define NS 16  // ring slots = 2*CH
#define NW (TT / CH)

typedef _Float16 v2h __attribute__((ext_vector_type(2)));
typedef _Float16 v8h __attribute__((ext_vector_type(8)));
typedef float v4f __attribute__((ext_vector_type(4)));

__device__ __forceinline__ float sig_(float x) {
  return __builtin_amdgcn_rcpf(1.f + __builtin_amdgcn_exp2f(-1.44269504f * x));
}
__device__ __forceinline__ float tanh_(float x) {
  return __builtin_fmaf(2.f, __builtin_amdgcn_rcpf(1.f + __builtin_amdgcn_exp2f(-2.88539008f * x)), -1.f);
}

template <int K>
__device__ __forceinline__ float qb_(float v) {
  return __int_as_float(__builtin_amdgcn_update_dpp(
      0, __float_as_int(v), (K | (K << 2) | (K << 4) | (K << 6)), 0xF, 0xF, true));
}

#if __has_builtin(__builtin_amdgcn_fdot2)
#define FDOT2(acc, a, b) (acc) = __builtin_amdgcn_fdot2((a), (b), (acc), false)
#else
#define FDOT2(acc, a, b) \
  (acc) = __builtin_fmaf((float)(a)[0], (float)(b)[0], \
          __builtin_fmaf((float)(a)[1], (float)(b)[1], (acc)))
#endif
#define KEEPP(a) asm volatile("" : "+v"(a))
#define PIN32(w)                                                            \
  do {                                                                      \
    _Pragma("unroll") for (int _i = 0; _i < 32; ++_i) KEEPP((w)[_i]);       \
  } while (0)
#define PIN16(w)                                                            \
  do {                                                                      \
    _Pragma("unroll") for (int _i = 0; _i < 16; ++_i) KEEPP((w)[_i]);       \
  } while (0)

// Spin until prog[i] >= v (acquire), sleeping between polls.
#define WAITP(i, v)                                                           \
  while (__hip_atomic_load(&prog[i], __ATOMIC_ACQUIRE,                        \
                           __HIP_MEMORY_SCOPE_WORKGROUP) < (v)) {             \
    __builtin_amdgcn_s_sleep(1);                                              \
  }
// Publish prog[i] = v after all this wave's data ds_writes retired.
#define POSTP(i, v)                                                           \
  do {                                                                        \
    asm volatile("s_waitcnt lgkmcnt(0)" ::: "memory");                        \
    if (lane == 0)                                                            \
      __hip_atomic_store(&prog[i], (v), __ATOMIC_RELEASE,                     \
                         __HIP_MEMORY_SCOPE_WORKGROUP);                       \
  } while (0)

__device__ __forceinline__ v2h bc2h_(int v) { return __builtin_bit_cast(v2h, v); }

// 64 halfs from LDS as 32 v2h via int4 reads (8x ds_read_b128, broadcast).
__device__ __forceinline__ void load_h64(const _Float16* p, v2h hv[32]) {
  const int4* hp = reinterpret_cast<const int4*>(p);
#pragma unroll
  for (int i = 0; i < 8; ++i) {
    int4 blk = hp[i];
    hv[4 * i + 0] = bc2h_(blk.x);
    hv[4 * i + 1] = bc2h_(blk.y);
    hv[4 * i + 2] = bc2h_(blk.z);
    hv[4 * i + 3] = bc2h_(blk.w);
  }
}

// fp32 row of 64 -> 32 v2h.
__device__ __forceinline__ void load_row16(const float* src, v2h dst[32]) {
  const float4* p = reinterpret_cast<const float4*>(src);
#pragma unroll
  for (int i = 0; i < 16; ++i) {
    float4 v = p[i];
    dst[2 * i]     = v2h{(_Float16)v.x, (_Float16)v.y};
    dst[2 * i + 1] = v2h{(_Float16)v.z, (_Float16)v.w};
  }
}

// fp32 row of 64 -> two 16-v2h halves (b-chain).
__device__ __forceinline__ void load_row_pair(const float* src, v2h* lo, v2h* hi) {
  const float4* p = reinterpret_cast<const float4*>(src);
#pragma unroll
  for (int i = 0; i < 8; ++i) {
    float4 v = p[i];
    lo[2 * i]     = v2h{(_Float16)v.x, (_Float16)v.y};
    lo[2 * i + 1] = v2h{(_Float16)v.z, (_Float16)v.w};
  }
#pragma unroll
  for (int i = 0; i < 8; ++i) {
    float4 v = p[8 + i];
    hi[2 * i]     = v2h{(_Float16)v.x, (_Float16)v.y};
    hi[2 * i + 1] = v2h{(_Float16)v.z, (_Float16)v.w};
  }
}

// W-fragment (A operand) for tile t, K-chunk kc of W[256x64] row-major f32.
// Lane l holds W[16t+(l&15)][32kc + kmap(j)] (R21-validated layout).
__device__ __forceinline__ v8h ldbfrag_(const float* W, int t, int kc, int lane) {
  const int row = 16 * t + (lane & 15);
  const float* p = W + row * 64 + 32 * kc + 4 * (lane >> 4);
  float4 fa = *reinterpret_cast<const float4*>(p);
  float4 fb = *reinterpret_cast<const float4*>(p + 16);
  return v8h{(_Float16)fa.x, (_Float16)fa.y, (_Float16)fa.z, (_Float16)fa.w,
             (_Float16)fb.x, (_Float16)fb.y, (_Float16)fb.z, (_Float16)fb.w};
}

// 4-gate rec dot, full-register weights (R17), even/odd split accumulators.
__device__ __forceinline__ void dot4_(const v2h w[4][32], const v2h hv[32],
                                      float& p0, float& p1, float& p2, float& p3) {
  float a0 = p0, a1 = p1, a2 = p2, a3 = p3;
  float b0 = 0.f, b1 = 0.f, b2 = 0.f, b3 = 0.f;
#pragma unroll
  for (int j = 0; j < 32; j += 2) {
    FDOT2(a0, w[0][j], hv[j]);         FDOT2(a1, w[1][j], hv[j]);
    FDOT2(a2, w[2][j], hv[j]);         FDOT2(a3, w[3][j], hv[j]);
    FDOT2(b0, w[0][j + 1], hv[j + 1]); FDOT2(b1, w[1][j + 1], hv[j + 1]);
    FDOT2(b2, w[2][j + 1], hv[j + 1]); FDOT2(b3, w[3][j + 1], hv[j + 1]);
  }
  p0 = a0 + b0; p1 = a1 + b1; p2 = a2 + b2; p3 = a3 + b3;
}

__global__ __attribute__((amdgpu_flat_work_group_size(384, 384),
                          amdgpu_waves_per_eu(2, 2)))
void lstm_pipe_k(
    const float* __restrict__ x,
    const float* __restrict__ wih_a0, const float* __restrict__ whh_a0,
    const float* __restrict__ bih_a0, const float* __restrict__ bhh_a0,
    const float* __restrict__ wih_a1, const float* __restrict__ whh_a1,
    const float* __restrict__ bih_a1, const float* __restrict__ bhh_a1,
    const float* __restrict__ wih_a2, const float* __restrict__ whh_a2,
    const float* __restrict__ bih_a2, const float* __restrict__ bhh_a2,
    const float* __restrict__ wih_b0, const float* __restrict__ whh_b0,
    const float* __restrict__ bih_b0, const float* __restrict__ bhh_b0,
    const float* __restrict__ wih_b1, const float* __restrict__ whh_b1,
    const float* __restrict__ bih_b1, const float* __restrict__ bhh_b1,
    const float* __restrict__ wih_b2, const float* __restrict__ whh_b2,
    const float* __restrict__ bih_b2, const float* __restrict__ bhh_b2,
    float* __restrict__ out)  // [B,T]
{
  const int b = blockIdx.x;
  const int tid = threadIdx.x;
  const int wave = tid >> 6;
  const int lane = tid & 63;

  __shared__ __align__(16) _Float16 hh[3][NS][64];  // h rings
  __shared__ __align__(16) float pj[2][NS][256];    // proj rings [hid][gate]
  __shared__ float xs[TT];
  __shared__ int prog[6];                           // per-wave windows done

  for (int i = tid; i < TT; i += 384) xs[i] = x[(size_t)b * TT + i];
  for (int i = tid; i < 3 * NS * 64 / 2; i += 384) reinterpret_cast<int*>(hh)[i] = 0;
  if (tid < 6) prog[tid] = 0;

  v2h wt[4][32];    // rec: full weights; b: wt[0]=lo, wt[1]=hi
  v8h bfr[16][2];   // proj MFMA waves: W A-fragments (AGPR)
  float bias[4] = {0.f, 0.f, 0.f, 0.f};
  float wi0_[4] = {0.f, 0.f, 0.f, 0.f};
  float whb0[4] = {}, wi1b[4] = {}, wh1b[4] = {}, bb1[4] = {},
        wi2b[4] = {}, wh2b[4] = {}, bb2[4] = {};

  if (wave == 0) {  // a0 recurrence
#pragma unroll
    for (int q = 0; q < 4; ++q) {
      const int row = q * 64 + lane;
      load_row16(whh_a0 + row * 64, wt[q]);
      bias[q] = bih_a0[row] + bhh_a0[row];
      wi0_[q] = wih_a0[row];
    }
    PIN32(wt[0]); PIN32(wt[1]); PIN32(wt[2]); PIN32(wt[3]);
  } else if (wave == 1) {  // a1 recurrence
#pragma unroll
    for (int q = 0; q < 4; ++q) {
      const int row = q * 64 + lane;
      load_row16(whh_a1 + row * 64, wt[q]);
      bias[q] = bih_a1[row] + bhh_a1[row];
    }
    PIN32(wt[0]); PIN32(wt[1]); PIN32(wt[2]); PIN32(wt[3]);
  } else if (wave == 2) {  // a2 recurrence
#pragma unroll
    for (int q = 0; q < 4; ++q) {
      const int row = q * 64 + lane;
      load_row16(whh_a2 + row * 64, wt[q]);
      bias[q] = bih_a2[row] + bhh_a2[row];
    }
    PIN32(wt[0]); PIN32(wt[1]); PIN32(wt[2]); PIN32(wt[3]);
  } else if (wave == 3) {  // b-chain
    const int q = lane & 3;
    load_row_pair(wih_b0 + q * 64, wt[0], wt[1]);
    bias[0] = bih_b0[q] + bhh_b0[q];
#pragma unroll
    for (int k = 0; k < 4; ++k) {
      whb0[k] = whh_b0[k];
      wi1b[k] = wih_b1[k]; wh1b[k] = whh_b1[k]; bb1[k] = bih_b1[k] + bhh_b1[k];
      wi2b[k] = wih_b2[k]; wh2b[k] = whh_b2[k]; bb2[k] = bih_b2[k] + bhh_b2[k];
    }
    PIN16(wt[0]); PIN16(wt[1]);
  } else if (wave == 4) {  // a1 proj MFMA: W = wih_a1
#pragma unroll
    for (int t = 0; t < 16; ++t) {
      bfr[t][0] = ldbfrag_(wih_a1, t, 0, lane);
      bfr[t][1] = ldbfrag_(wih_a1, t, 1, lane);
    }
  } else {                 // wave 5: a2 proj MFMA: W = wih_a2
#pragma unroll
    for (int t = 0; t < 16; ++t) {
      bfr[t][0] = ldbfrag_(wih_a2, t, 0, lane);
      bfr[t][1] = ldbfrag_(wih_a2, t, 1, lane);
    }
  }
  __syncthreads();

  float c = 0.f;
  float h0b = 0.f, c0b = 0.f, h1b = 0.f, c1b = 0.f, h2b = 0.f, c2b = 0.f;

  if (wave == 0) {  // a0 rec -> hh[0]; consumer w4
    __builtin_amdgcn_s_setprio(1);
    for (int k = 0; k < NW; ++k) {
      if (k >= 2) { WAITP(4, k - 1); }
      const int t0 = k * CH;
      for (int s = 0; s < CH; ++s) {
        const int t = t0 + s;
        v2h hv[32];
        load_h64(&hh[0][(t + NS - 1) & (NS - 1)][0], hv);
        const float xv = xs[t];
        float p0 = bias[0], p1 = bias[1], p2 = bias[2], p3 = bias[3];
        dot4_(wt, hv, p0, p1, p2, p3);
        p0 = __builtin_fmaf(wi0_[0], xv, p0);
        p1 = __builtin_fmaf(wi0_[1], xv, p1);
        p2 = __builtin_fmaf(wi0_[2], xv, p2);
        p3 = __builtin_fmaf(wi0_[3], xv, p3);
        float gi = sig_(p0), gf = sig_(p1), gg = tanh_(p2), go = sig_(p3);
        c = __builtin_fmaf(gf, c, gi * gg);
        hh[0][t & (NS - 1)][lane] = (_Float16)(go * tanh_(c));
      }
      POSTP(0, k + 1);
    }
    __builtin_amdgcn_s_setprio(0);
  } else if (wave == 1) {  // a1 rec: reads pj[0]; -> hh[1]; consumer w5
    __builtin_amdgcn_s_setprio(1);
    for (int k = 0; k < NW; ++k) {
      WAITP(4, k + 1);
      if (k >= 2) { WAITP(5, k - 1); }
      const int t0 = k * CH;
      for (int s = 0; s < CH; ++s) {
        const int t = t0 + s;
        v2h hv[32];
        load_h64(&hh[1][(t + NS - 1) & (NS - 1)][0], hv);
        float4 pr = *reinterpret_cast<const float4*>(&pj[0][t & (NS - 1)][lane * 4]);
        float p0 = bias[0], p1 = bias[1], p2 = bias[2], p3 = bias[3];
        dot4_(wt, hv, p0, p1, p2, p3);
        p0 += pr.x; p1 += pr.y; p2 += pr.z; p3 += pr.w;
        float gi = sig_(p0), gf = sig_(p1), gg = tanh_(p2), go = sig_(p3);
        c = __builtin_fmaf(gf, c, gi * gg);
        hh[1][t & (NS - 1)][lane] = (_Float16)(go * tanh_(c));
      }
      POSTP(1, k + 1);
    }
    __builtin_amdgcn_s_setprio(0);
  } else if (wave == 2) {  // a2 rec: reads pj[1]; -> hh[2]; consumer w3
    __builtin_amdgcn_s_setprio(1);
    for (int k = 0; k < NW; ++k) {
      WAITP(5, k + 1);
      if (k >= 2) { WAITP(3, k - 1); }
      const int t0 = k * CH;
      for (int s = 0; s < CH; ++s) {
        const int t = t0 + s;
        v2h hv[32];
        load_h64(&hh[2][(t + NS - 1) & (NS - 1)][0], hv);
        float4 pr = *reinterpret_cast<const float4*>(&pj[1][t & (NS - 1)][lane * 4]);
        float p0 = bias[0], p1 = bias[1], p2 = bias[2], p3 = bias[3];
        dot4_(wt, hv, p0, p1, p2, p3);
        p0 += pr.x; p1 += pr.y; p2 += pr.z; p3 += pr.w;
        float gi = sig_(p0), gf = sig_(p1), gg = tanh_(p2), go = sig_(p3);
        c = __builtin_fmaf(gf, c, gi * gg);
        hh[2][t & (NS - 1)][lane] = (_Float16)(go * tanh_(c));
      }
      POSTP(2, k + 1);
    }
    __builtin_amdgcn_s_setprio(0);
  } else if (wave == 3) {  // b-chain: reads hh[2]
    for (int k = 0; k < NW; ++k) {
      WAITP(2, k + 1);
      const int t0 = k * CH;
      for (int s = 0; s < CH; ++s) {
        const int t = t0 + s;
        v2h hv[32];
        load_h64(&hh[2][t & (NS - 1)][0], hv);
        float pga = bias[0], pgb = 0.f;
#pragma unroll
        for (int j = 0; j < 16; ++j) {
          FDOT2(pga, wt[0][j], hv[j]);
          FDOT2(pgb, wt[1][j], hv[16 + j]);
        }
        float pg = pga + pgb;
        float p_i = qb_<0>(pg), p_f = qb_<1>(pg), p_g = qb_<2>(pg), p_o = qb_<3>(pg);
        float i0 = sig_(__builtin_fmaf(whb0[0], h0b, p_i));
        float f0 = sig_(__builtin_fmaf(whb0[1], h0b, p_f));
        float g0 = tanh_(__builtin_fmaf(whb0[2], h0b, p_g));
        float o0 = sig_(__builtin_fmaf(whb0[3], h0b, p_o));
        c0b = __builtin_fmaf(f0, c0b, i0 * g0);
        h0b = o0 * tanh_(c0b);
        float i1 = sig_(bb1[0] + __builtin_fmaf(wi1b[0], h0b, wh1b[0] * h1b));
        float f1 = sig_(bb1[1] + __builtin_fmaf(wi1b[1], h0b, wh1b[1] * h1b));
        float g1 = tanh_(bb1[2] + __builtin_fmaf(wi1b[2], h0b, wh1b[2] * h1b));
        float o1 = sig_(bb1[3] + __builtin_fmaf(wi1b[3], h0b, wh1b[3] * h1b));
        c1b = __builtin_fmaf(f1, c1b, i1 * g1);
        h1b = o1 * tanh_(c1b);
        float i2 = sig_(bb2[0] + __builtin_fmaf(wi2b[0], h1b, wh2b[0] * h2b));
        float f2 = sig_(bb2[1] + __builtin_fmaf(wi2b[1], h1b, wh2b[1] * h2b));
        float g2 = tanh_(bb2[2] + __builtin_fmaf(wi2b[2], h1b, wh2b[2] * h2b));
        float o2 = sig_(bb2[3] + __builtin_fmaf(wi2b[3], h1b, wh2b[3] * h2b));
        c2b = __builtin_fmaf(f2, c2b, i2 * g2);
        h2b = o2 * tanh_(c2b);
        if (lane == 0) out[(size_t)b * TT + t] = h2b;
      }
      POSTP(3, k + 1);
    }
  } else if (wave == 4) {  // a1 proj MFMA: hh[0] window k -> pj[0] window k
    for (int k = 0; k < NW; ++k) {
      WAITP(0, k + 1);
      if (k >= 2) { WAITP(1, k - 1); }
      const int t0 = k * CH;
      const int slotb = (t0 + (lane & 15)) & (NS - 1);
      const char* hp = (const char*)(&hh[0][slotb][0]) + 8 * (lane >> 4);
      int2 r00 = *(const int2*)(hp);        // kc0 j0..3
      int2 r01 = *(const int2*)(hp + 32);   // kc0 j4..7
      int2 r10 = *(const int2*)(hp + 64);   // kc1 j0..3
      int2 r11 = *(const int2*)(hp + 96);   // kc1 j4..7
      v8h Bf0 = __builtin_bit_cast(v8h, int4{r00.x, r00.y, r01.x, r01.y});
      v8h Bf1 = __builtin_bit_cast(v8h, int4{r10.x, r10.y, r11.x, r11.y});
      float* pbase = &pj[0][slotb][0] + 16 * (lane >> 4);
      const bool wr = (lane & 15) < 8;  // cols 8-15 are garbage (unused slots)
      const v4f z = {0.f, 0.f, 0.f, 0.f};
#pragma unroll
      for (int tl = 0; tl < 16; ++tl) {
        v4f acc = __builtin_amdgcn_mfma_f32_16x16x32_f16(bfr[tl][0], Bf0, z, 0, 0, 0);
        acc = __builtin_amdgcn_mfma_f32_16x16x32_f16(bfr[tl][1], Bf1, acc, 0, 0, 0);
        if (wr) {
          const int o = 64 * (tl & 3) + (tl >> 2);
          pbase[o] = acc[0]; pbase[o + 4] = acc[1];
          pbase[o + 8] = acc[2]; pbase[o + 12] = acc[3];
        }
        __builtin_amdgcn_sched_barrier(0);
      }
      POSTP(4, k + 1);
    }
  } else {                 // wave 5: a2 proj MFMA: hh[1] window k -> pj[1]
    for (int k = 0; k < NW; ++k) {
      WAITP(1, k + 1);
      if (k >= 2) { WAITP(2, k - 1); }
      const int t0 = k * CH;
      const int slotb = (t0 + (lane & 15)) & (NS - 1);
      const char* hp = (const char*)(&hh[1][slotb][0]) + 8 * (lane >> 4);
      int2 r00 = *(const int2*)(hp);
      int2 r01 = *(const int2*)(hp + 32);
      int2 r10 = *(const int2*)(hp + 64);
      int2 r11 = *(const int2*)(hp + 96);
      v8h Bf0 = __builtin_bit_cast(v8h, int4{r00.x, r00.y, r01.x, r01.y});
      v8h Bf1 = __builtin_bit_cast(v8h, int4{r10.x, r10.y, r11.x, r11.y});
      float* pbase = &pj[1][slotb][0] + 16 * (lane >> 4);
      const bool wr = (lane & 15) < 8;
      const v4f z = {0.f, 0.f, 0.f, 0.f};
#pragma unroll
      for (int tl = 0; tl < 16; ++tl) {
        v4f acc = __builtin_amdgcn_mfma_f32_16x16x32_f16(bfr[tl][0], Bf0, z, 0, 0, 0);
        acc = __builtin_amdgcn_mfma_f32_16x16x32_f16(bfr[tl][1], Bf1, acc, 0, 0, 0);
        if (wr) {
          const int o = 64 * (tl & 3) + (tl >> 2);
          pbase[o] = acc[0]; pbase[o + 4] = acc[1];
          pbase[o + 8] = acc[2]; pbase[o + 12] = acc[3];
        }
        __builtin_amdgcn_sched_barrier(0);
      }
      POSTP(5, k + 1);
    }
  }
}

extern "C" void kernel_launch(void* const* d_in, const int* in_sizes, int n_in,
                              void* d_out, int out_size, void* d_ws, size_t ws_size,
                              hipStream_t stream) {
  const float* x      = (const float*)d_in[0];
  const float* wih_a0 = (const float*)d_in[1];
  const float* whh_a0 = (const float*)d_in[2];
  const float* bih_a0 = (const float*)d_in[3];
  const float* bhh_a0 = (const float*)d_in[4];
  const float* wih_a1 = (const float*)d_in[5];
  const float* whh_a1 = (const float*)d_in[6];
  const float* bih_a1 = (const float*)d_in[7];
  const float* bhh_a1 = (const float*)d_in[8];
  const float* wih_a2 = (const float*)d_in[9];
  const float* whh_a2 = (const float*)d_in[10];
  const float* bih_a2 = (const float*)d_in[11];
  const float* bhh_a2 = (const float*)d_in[12];
  const float* wih_b0 = (const float*)d_in[13];
  const float* whh_b0 = (const float*)d_in[14];
  const float* bih_b0 = (const float*)d_in[15];
  const float* bhh_b0 = (const float*)d_in[16];
  const float* wih_b1 = (const float*)d_in[17];
  const float* whh_b1 = (const float*)d_in[18];
  const float* bih_b1 = (const float*)d_in[19];
  const float* bhh_b1 = (const float*)d_in[20];
  const float* wih_b2 = (const float*)d_in[21];
  const float* whh_b2 = (const float*)d_in[22];
  const float* bih_b2 = (const float*)d_in[23];
  const float* bhh_b2 = (const float*)d_in[24];
  float* out = (float*)d_out;

  lstm_pipe_k<<<BB, 384, 0, stream>>>(
      x,
      wih_a0, whh_a0, bih_a0, bhh_a0,
      wih_a1, whh_a1, bih_a1, bhh_a1,
      wih_a2, whh_a2, bih_a2, bhh_a2,
      wih_b0, whh_b0, bih_b0, bhh_b0,
      wih_b1, whh_b1, bih_b1, bhh_b1,
      wih_b2, whh_b2, bih_b2, bhh_b2,
      out);
}

// Round 11
// 347.531 us; speedup vs baseline: 1.1824x; 1.1196x over previous
//
#include <hip/hip_runtime.h>

// AttackLSTM R26 — R25 + register overlay (union) + ring de-conflict padding.
// R25 post-mortem: steady 326us with TWO pathologies. (1) WRITE 59MB spill:
// wt[4][32] (128r) and bfr[16][2] (128r) both function-scope -> compiler
// can't prove per-wave exclusivity -> union-liveness 256r -> scratch.
// Fix: C union overlay (per-wave exclusive by construction). (2) bank
// conflicts 3.7e7: MFMA B-read has lanes 0-15 on 16 DIFFERENT hh slots,
// slot stride 128B = 0 mod 32 banks -> all on bank 0 (16-way); pj scatter
// writes same (1024B rows). Fix: pad hh rows 64->72 halfs (144B, 16B-
// aligned; slot base bank = 4*slot mod 32 -> 2/bank = free), pj rows
// 256->260 floats (1040B). Everything else verbatim R25 (absmax=0
// validated: MFMA proj D-mapping, self-timed prog[6], 6-wave placement
// w0-2 rec S0-2 | w3 b S3 | w4,5 MFMA-proj S0,S1).
// Verify: WRITE ~512KB, conflicts <=2e6, dur 230-280us.

#define BB 256
#define TT 512
#define CH 8
#define NS 16  // ring slots = 2*CH
#define NW (TT / CH)
#define HP 72   // padded hh row (halfs): 144B = 9x16B
#define PP 260  // padded pj row (floats): 1040B

typedef _Float16 v2h __attribute__((ext_vector_type(2)));
typedef _Float16 v8h __attribute__((ext_vector_type(8)));
typedef float v4f __attribute__((ext_vector_type(4)));

__device__ __forceinline__ float sig_(float x) {
  return __builtin_amdgcn_rcpf(1.f + __builtin_amdgcn_exp2f(-1.44269504f * x));
}
__device__ __forceinline__ float tanh_(float x) {
  return __builtin_fmaf(2.f, __builtin_amdgcn_rcpf(1.f + __builtin_amdgcn_exp2f(-2.88539008f * x)), -1.f);
}

template <int K>
__device__ __forceinline__ float qb_(float v) {
  return __int_as_float(__builtin_amdgcn_update_dpp(
      0, __float_as_int(v), (K | (K << 2) | (K << 4) | (K << 6)), 0xF, 0xF, true));
}

#if __has_builtin(__builtin_amdgcn_fdot2)
#define FDOT2(acc, a, b) (acc) = __builtin_amdgcn_fdot2((a), (b), (acc), false)
#else
#define FDOT2(acc, a, b) \
  (acc) = __builtin_fmaf((float)(a)[0], (float)(b)[0], \
          __builtin_fmaf((float)(a)[1], (float)(b)[1], (acc)))
#endif
#define KEEPP(a) asm volatile("" : "+v"(a))
#define PIN32(w)                                                            \
  do {                                                                      \
    _Pragma("unroll") for (int _i = 0; _i < 32; ++_i) KEEPP((w)[_i]);       \
  } while (0)
#define PIN16(w)                                                            \
  do {                                                                      \
    _Pragma("unroll") for (int _i = 0; _i < 16; ++_i) KEEPP((w)[_i]);       \
  } while (0)

// Spin until prog[i] >= v (acquire), sleeping between polls.
#define WAITP(i, v)                                                           \
  while (__hip_atomic_load(&prog[i], __ATOMIC_ACQUIRE,                        \
                           __HIP_MEMORY_SCOPE_WORKGROUP) < (v)) {             \
    __builtin_amdgcn_s_sleep(1);                                              \
  }
// Publish prog[i] = v after all this wave's data ds_writes retired.
#define POSTP(i, v)                                                           \
  do {                                                                        \
    asm volatile("s_waitcnt lgkmcnt(0)" ::: "memory");                        \
    if (lane == 0)                                                            \
      __hip_atomic_store(&prog[i], (v), __ATOMIC_RELEASE,                     \
                         __HIP_MEMORY_SCOPE_WORKGROUP);                       \
  } while (0)

__device__ __forceinline__ v2h bc2h_(int v) { return __builtin_bit_cast(v2h, v); }

// 64 halfs from LDS as 32 v2h via int4 reads (8x ds_read_b128, broadcast).
__device__ __forceinline__ void load_h64(const _Float16* p, v2h hv[32]) {
  const int4* hp = reinterpret_cast<const int4*>(p);
#pragma unroll
  for (int i = 0; i < 8; ++i) {
    int4 blk = hp[i];
    hv[4 * i + 0] = bc2h_(blk.x);
    hv[4 * i + 1] = bc2h_(blk.y);
    hv[4 * i + 2] = bc2h_(blk.z);
    hv[4 * i + 3] = bc2h_(blk.w);
  }
}

// fp32 row of 64 -> 32 v2h.
__device__ __forceinline__ void load_row16(const float* src, v2h dst[32]) {
  const float4* p = reinterpret_cast<const float4*>(src);
#pragma unroll
  for (int i = 0; i < 16; ++i) {
    float4 v = p[i];
    dst[2 * i]     = v2h{(_Float16)v.x, (_Float16)v.y};
    dst[2 * i + 1] = v2h{(_Float16)v.z, (_Float16)v.w};
  }
}

// fp32 row of 64 -> two 16-v2h halves (b-chain).
__device__ __forceinline__ void load_row_pair(const float* src, v2h* lo, v2h* hi) {
  const float4* p = reinterpret_cast<const float4*>(src);
#pragma unroll
  for (int i = 0; i < 8; ++i) {
    float4 v = p[i];
    lo[2 * i]     = v2h{(_Float16)v.x, (_Float16)v.y};
    lo[2 * i + 1] = v2h{(_Float16)v.z, (_Float16)v.w};
  }
#pragma unroll
  for (int i = 0; i < 8; ++i) {
    float4 v = p[8 + i];
    hi[2 * i]     = v2h{(_Float16)v.x, (_Float16)v.y};
    hi[2 * i + 1] = v2h{(_Float16)v.z, (_Float16)v.w};
  }
}

// W-fragment (A operand) for tile t, K-chunk kc of W[256x64] row-major f32.
__device__ __forceinline__ v8h ldbfrag_(const float* W, int t, int kc, int lane) {
  const int row = 16 * t + (lane & 15);
  const float* p = W + row * 64 + 32 * kc + 4 * (lane >> 4);
  float4 fa = *reinterpret_cast<const float4*>(p);
  float4 fb = *reinterpret_cast<const float4*>(p + 16);
  return v8h{(_Float16)fa.x, (_Float16)fa.y, (_Float16)fa.z, (_Float16)fa.w,
             (_Float16)fb.x, (_Float16)fb.y, (_Float16)fb.z, (_Float16)fb.w};
}

// 4-gate rec dot, full-register weights, even/odd split accumulators.
__device__ __forceinline__ void dot4_(const v2h w[4][32], const v2h hv[32],
                                      float& p0, float& p1, float& p2, float& p3) {
  float a0 = p0, a1 = p1, a2 = p2, a3 = p3;
  float b0 = 0.f, b1 = 0.f, b2 = 0.f, b3 = 0.f;
#pragma unroll
  for (int j = 0; j < 32; j += 2) {
    FDOT2(a0, w[0][j], hv[j]);         FDOT2(a1, w[1][j], hv[j]);
    FDOT2(a2, w[2][j], hv[j]);         FDOT2(a3, w[3][j], hv[j]);
    FDOT2(b0, w[0][j + 1], hv[j + 1]); FDOT2(b1, w[1][j + 1], hv[j + 1]);
    FDOT2(b2, w[2][j + 1], hv[j + 1]); FDOT2(b3, w[3][j + 1], hv[j + 1]);
  }
  p0 = a0 + b0; p1 = a1 + b1; p2 = a2 + b2; p3 = a3 + b3;
}

__global__ __attribute__((amdgpu_flat_work_group_size(384, 384),
                          amdgpu_waves_per_eu(2, 2)))
void lstm_pipe_k(
    const float* __restrict__ x,
    const float* __restrict__ wih_a0, const float* __restrict__ whh_a0,
    const float* __restrict__ bih_a0, const float* __restrict__ bhh_a0,
    const float* __restrict__ wih_a1, const float* __restrict__ whh_a1,
    const float* __restrict__ bih_a1, const float* __restrict__ bhh_a1,
    const float* __restrict__ wih_a2, const float* __restrict__ whh_a2,
    const float* __restrict__ bih_a2, const float* __restrict__ bhh_a2,
    const float* __restrict__ wih_b0, const float* __restrict__ whh_b0,
    const float* __restrict__ bih_b0, const float* __restrict__ bhh_b0,
    const float* __restrict__ wih_b1, const float* __restrict__ whh_b1,
    const float* __restrict__ bih_b1, const float* __restrict__ bhh_b1,
    const float* __restrict__ wih_b2, const float* __restrict__ whh_b2,
    const float* __restrict__ bih_b2, const float* __restrict__ bhh_b2,
    float* __restrict__ out)  // [B,T]
{
  const int b = blockIdx.x;
  const int tid = threadIdx.x;
  const int wave = tid >> 6;
  const int lane = tid & 63;

  __shared__ __align__(16) _Float16 hh[3][NS][HP];  // h rings (padded rows)
  __shared__ __align__(16) float pj[2][NS][PP];     // proj rings (padded rows)
  __shared__ float xs[TT];
  __shared__ int prog[6];                           // per-wave windows done

  for (int i = tid; i < TT; i += 384) xs[i] = x[(size_t)b * TT + i];
  for (int i = tid; i < 3 * NS * HP / 2; i += 384) reinterpret_cast<int*>(hh)[i] = 0;
  if (tid < 6) prog[tid] = 0;

  // Register overlay: rec/b waves use u.wt; MFMA proj waves use u.bfr.
  // Per-wave exclusive -> shared storage kills the R25 union-liveness spill.
  union UW {
    v2h wt[4][32];
    v8h bfr[16][2];
  } u;

  float bias[4] = {0.f, 0.f, 0.f, 0.f};
  float wi0_[4] = {0.f, 0.f, 0.f, 0.f};
  float whb0[4] = {}, wi1b[4] = {}, wh1b[4] = {}, bb1[4] = {},
        wi2b[4] = {}, wh2b[4] = {}, bb2[4] = {};

  if (wave == 0) {  // a0 recurrence
#pragma unroll
    for (int q = 0; q < 4; ++q) {
      const int row = q * 64 + lane;
      load_row16(whh_a0 + row * 64, u.wt[q]);
      bias[q] = bih_a0[row] + bhh_a0[row];
      wi0_[q] = wih_a0[row];
    }
    PIN32(u.wt[0]); PIN32(u.wt[1]); PIN32(u.wt[2]); PIN32(u.wt[3]);
  } else if (wave == 1) {  // a1 recurrence
#pragma unroll
    for (int q = 0; q < 4; ++q) {
      const int row = q * 64 + lane;
      load_row16(whh_a1 + row * 64, u.wt[q]);
      bias[q] = bih_a1[row] + bhh_a1[row];
    }
    PIN32(u.wt[0]); PIN32(u.wt[1]); PIN32(u.wt[2]); PIN32(u.wt[3]);
  } else if (wave == 2) {  // a2 recurrence
#pragma unroll
    for (int q = 0; q < 4; ++q) {
      const int row = q * 64 + lane;
      load_row16(whh_a2 + row * 64, u.wt[q]);
      bias[q] = bih_a2[row] + bhh_a2[row];
    }
    PIN32(u.wt[0]); PIN32(u.wt[1]); PIN32(u.wt[2]); PIN32(u.wt[3]);
  } else if (wave == 3) {  // b-chain
    const int q = lane & 3;
    load_row_pair(wih_b0 + q * 64, u.wt[0], u.wt[1]);
    bias[0] = bih_b0[q] + bhh_b0[q];
#pragma unroll
    for (int k = 0; k < 4; ++k) {
      whb0[k] = whh_b0[k];
      wi1b[k] = wih_b1[k]; wh1b[k] = whh_b1[k]; bb1[k] = bih_b1[k] + bhh_b1[k];
      wi2b[k] = wih_b2[k]; wh2b[k] = whh_b2[k]; bb2[k] = bih_b2[k] + bhh_b2[k];
    }
    PIN16(u.wt[0]); PIN16(u.wt[1]);
  } else if (wave == 4) {  // a1 proj MFMA: W = wih_a1
#pragma unroll
    for (int t = 0; t < 16; ++t) {
      u.bfr[t][0] = ldbfrag_(wih_a1, t, 0, lane);
      u.bfr[t][1] = ldbfrag_(wih_a1, t, 1, lane);
    }
  } else {                 // wave 5: a2 proj MFMA: W = wih_a2
#pragma unroll
    for (int t = 0; t < 16; ++t) {
      u.bfr[t][0] = ldbfrag_(wih_a2, t, 0, lane);
      u.bfr[t][1] = ldbfrag_(wih_a2, t, 1, lane);
    }
  }
  __syncthreads();

  float c = 0.f;
  float h0b = 0.f, c0b = 0.f, h1b = 0.f, c1b = 0.f, h2b = 0.f, c2b = 0.f;

  if (wave == 0) {  // a0 rec -> hh[0]; consumer w4
    __builtin_amdgcn_s_setprio(1);
    for (int k = 0; k < NW; ++k) {
      if (k >= 2) { WAITP(4, k - 1); }
      const int t0 = k * CH;
      for (int s = 0; s < CH; ++s) {
        const int t = t0 + s;
        v2h hv[32];
        load_h64(&hh[0][(t + NS - 1) & (NS - 1)][0], hv);
        const float xv = xs[t];
        float p0 = bias[0], p1 = bias[1], p2 = bias[2], p3 = bias[3];
        dot4_(u.wt, hv, p0, p1, p2, p3);
        p0 = __builtin_fmaf(wi0_[0], xv, p0);
        p1 = __builtin_fmaf(wi0_[1], xv, p1);
        p2 = __builtin_fmaf(wi0_[2], xv, p2);
        p3 = __builtin_fmaf(wi0_[3], xv, p3);
        float gi = sig_(p0), gf = sig_(p1), gg = tanh_(p2), go = sig_(p3);
        c = __builtin_fmaf(gf, c, gi * gg);
        hh[0][t & (NS - 1)][lane] = (_Float16)(go * tanh_(c));
      }
      POSTP(0, k + 1);
    }
    __builtin_amdgcn_s_setprio(0);
  } else if (wave == 1) {  // a1 rec: reads pj[0]; -> hh[1]; consumer w5
    __builtin_amdgcn_s_setprio(1);
    for (int k = 0; k < NW; ++k) {
      WAITP(4, k + 1);
      if (k >= 2) { WAITP(5, k - 1); }
      const int t0 = k * CH;
      for (int s = 0; s < CH; ++s) {
        const int t = t0 + s;
        v2h hv[32];
        load_h64(&hh[1][(t + NS - 1) & (NS - 1)][0], hv);
        float4 pr = *reinterpret_cast<const float4*>(&pj[0][t & (NS - 1)][lane * 4]);
        float p0 = bias[0], p1 = bias[1], p2 = bias[2], p3 = bias[3];
        dot4_(u.wt, hv, p0, p1, p2, p3);
        p0 += pr.x; p1 += pr.y; p2 += pr.z; p3 += pr.w;
        float gi = sig_(p0), gf = sig_(p1), gg = tanh_(p2), go = sig_(p3);
        c = __builtin_fmaf(gf, c, gi * gg);
        hh[1][t & (NS - 1)][lane] = (_Float16)(go * tanh_(c));
      }
      POSTP(1, k + 1);
    }
    __builtin_amdgcn_s_setprio(0);
  } else if (wave == 2) {  // a2 rec: reads pj[1]; -> hh[2]; consumer w3
    __builtin_amdgcn_s_setprio(1);
    for (int k = 0; k < NW; ++k) {
      WAITP(5, k + 1);
      if (k >= 2) { WAITP(3, k - 1); }
      const int t0 = k * CH;
      for (int s = 0; s < CH; ++s) {
        const int t = t0 + s;
        v2h hv[32];
        load_h64(&hh[2][(t + NS - 1) & (NS - 1)][0], hv);
        float4 pr = *reinterpret_cast<const float4*>(&pj[1][t & (NS - 1)][lane * 4]);
        float p0 = bias[0], p1 = bias[1], p2 = bias[2], p3 = bias[3];
        dot4_(u.wt, hv, p0, p1, p2, p3);
        p0 += pr.x; p1 += pr.y; p2 += pr.z; p3 += pr.w;
        float gi = sig_(p0), gf = sig_(p1), gg = tanh_(p2), go = sig_(p3);
        c = __builtin_fmaf(gf, c, gi * gg);
        hh[2][t & (NS - 1)][lane] = (_Float16)(go * tanh_(c));
      }
      POSTP(2, k + 1);
    }
    __builtin_amdgcn_s_setprio(0);
  } else if (wave == 3) {  // b-chain: reads hh[2]
    for (int k = 0; k < NW; ++k) {
      WAITP(2, k + 1);
      const int t0 = k * CH;
      for (int s = 0; s < CH; ++s) {
        const int t = t0 + s;
        v2h hv[32];
        load_h64(&hh[2][t & (NS - 1)][0], hv);
        float pga = bias[0], pgb = 0.f;
#pragma unroll
        for (int j = 0; j < 16; ++j) {
          FDOT2(pga, u.wt[0][j], hv[j]);
          FDOT2(pgb, u.wt[1][j], hv[16 + j]);
        }
        float pg = pga + pgb;
        float p_i = qb_<0>(pg), p_f = qb_<1>(pg), p_g = qb_<2>(pg), p_o = qb_<3>(pg);
        float i0 = sig_(__builtin_fmaf(whb0[0], h0b, p_i));
        float f0 = sig_(__builtin_fmaf(whb0[1], h0b, p_f));
        float g0 = tanh_(__builtin_fmaf(whb0[2], h0b, p_g));
        float o0 = sig_(__builtin_fmaf(whb0[3], h0b, p_o));
        c0b = __builtin_fmaf(f0, c0b, i0 * g0);
        h0b = o0 * tanh_(c0b);
        float i1 = sig_(bb1[0] + __builtin_fmaf(wi1b[0], h0b, wh1b[0] * h1b));
        float f1 = sig_(bb1[1] + __builtin_fmaf(wi1b[1], h0b, wh1b[1] * h1b));
        float g1 = tanh_(bb1[2] + __builtin_fmaf(wi1b[2], h0b, wh1b[2] * h1b));
        float o1 = sig_(bb1[3] + __builtin_fmaf(wi1b[3], h0b, wh1b[3] * h1b));
        c1b = __builtin_fmaf(f1, c1b, i1 * g1);
        h1b = o1 * tanh_(c1b);
        float i2 = sig_(bb2[0] + __builtin_fmaf(wi2b[0], h1b, wh2b[0] * h2b));
        float f2 = sig_(bb2[1] + __builtin_fmaf(wi2b[1], h1b, wh2b[1] * h2b));
        float g2 = tanh_(bb2[2] + __builtin_fmaf(wi2b[2], h1b, wh2b[2] * h2b));
        float o2 = sig_(bb2[3] + __builtin_fmaf(wi2b[3], h1b, wh2b[3] * h2b));
        c2b = __builtin_fmaf(f2, c2b, i2 * g2);
        h2b = o2 * tanh_(c2b);
        if (lane == 0) out[(size_t)b * TT + t] = h2b;
      }
      POSTP(3, k + 1);
    }
  } else if (wave == 4) {  // a1 proj MFMA: hh[0] window k -> pj[0] window k
    for (int k = 0; k < NW; ++k) {
      WAITP(0, k + 1);
      if (k >= 2) { WAITP(1, k - 1); }
      const int t0 = k * CH;
      const int slotb = (t0 + (lane & 15)) & (NS - 1);
      const char* hp = (const char*)(&hh[0][slotb][0]) + 8 * (lane >> 4);
      int2 r00 = *(const int2*)(hp);        // kc0 j0..3
      int2 r01 = *(const int2*)(hp + 32);   // kc0 j4..7
      int2 r10 = *(const int2*)(hp + 64);   // kc1 j0..3
      int2 r11 = *(const int2*)(hp + 96);   // kc1 j4..7
      v8h Bf0 = __builtin_bit_cast(v8h, int4{r00.x, r00.y, r01.x, r01.y});
      v8h Bf1 = __builtin_bit_cast(v8h, int4{r10.x, r10.y, r11.x, r11.y});
      float* pbase = &pj[0][slotb][0] + 16 * (lane >> 4);
      const bool wr = (lane & 15) < 8;  // cols 8-15 garbage (other ring half)
      const v4f z = {0.f, 0.f, 0.f, 0.f};
#pragma unroll
      for (int tl = 0; tl < 16; ++tl) {
        v4f acc = __builtin_amdgcn_mfma_f32_16x16x32_f16(u.bfr[tl][0], Bf0, z, 0, 0, 0);
        acc = __builtin_amdgcn_mfma_f32_16x16x32_f16(u.bfr[tl][1], Bf1, acc, 0, 0, 0);
        if (wr) {
          const int o = 64 * (tl & 3) + (tl >> 2);
          pbase[o] = acc[0]; pbase[o + 4] = acc[1];
          pbase[o + 8] = acc[2]; pbase[o + 12] = acc[3];
        }
        __builtin_amdgcn_sched_barrier(0);
      }
      POSTP(4, k + 1);
    }
  } else {                 // wave 5: a2 proj MFMA: hh[1] window k -> pj[1]
    for (int k = 0; k < NW; ++k) {
      WAITP(1, k + 1);
      if (k >= 2) { WAITP(2, k - 1); }
      const int t0 = k * CH;
      const int slotb = (t0 + (lane & 15)) & (NS - 1);
      const char* hp = (const char*)(&hh[1][slotb][0]) + 8 * (lane >> 4);
      int2 r00 = *(const int2*)(hp);
      int2 r01 = *(const int2*)(hp + 32);
      int2 r10 = *(const int2*)(hp + 64);
      int2 r11 = *(const int2*)(hp + 96);
      v8h Bf0 = __builtin_bit_cast(v8h, int4{r00.x, r00.y, r01.x, r01.y});
      v8h Bf1 = __builtin_bit_cast(v8h, int4{r10.x, r10.y, r11.x, r11.y});
      float* pbase = &pj[1][slotb][0] + 16 * (lane >> 4);
      const bool wr = (lane & 15) < 8;
      const v4f z = {0.f, 0.f, 0.f, 0.f};
#pragma unroll
      for (int tl = 0; tl < 16; ++tl) {
        v4f acc = __builtin_amdgcn_mfma_f32_16x16x32_f16(u.bfr[tl][0], Bf0, z, 0, 0, 0);
        acc = __builtin_amdgcn_mfma_f32_16x16x32_f16(u.bfr[tl][1], Bf1, acc, 0, 0, 0);
        if (wr) {
          const int o = 64 * (tl & 3) + (tl >> 2);
          pbase[o] = acc[0]; pbase[o + 4] = acc[1];
          pbase[o + 8] = acc[2]; pbase[o + 12] = acc[3];
        }
        __builtin_amdgcn_sched_barrier(0);
      }
      POSTP(5, k + 1);
    }
  }
}

extern "C" void kernel_launch(void* const* d_in, const int* in_sizes, int n_in,
                              void* d_out, int out_size, void* d_ws, size_t ws_size,
                              hipStream_t stream) {
  const float* x      = (const float*)d_in[0];
  const float* wih_a0 = (const float*)d_in[1];
  const float* whh_a0 = (const float*)d_in[2];
  const float* bih_a0 = (const float*)d_in[3];
  const float* bhh_a0 = (const float*)d_in[4];
  const float* wih_a1 = (const float*)d_in[5];
  const float* whh_a1 = (const float*)d_in[6];
  const float* bih_a1 = (const float*)d_in[7];
  const float* bhh_a1 = (const float*)d_in[8];
  const float* wih_a2 = (const float*)d_in[9];
  const float* whh_a2 = (const float*)d_in[10];
  const float* bih_a2 = (const float*)d_in[11];
  const float* bhh_a2 = (const float*)d_in[12];
  const float* wih_b0 = (const float*)d_in[13];
  const float* whh_b0 = (const float*)d_in[14];
  const float* bih_b0 = (const float*)d_in[15];
  const float* bhh_b0 = (const float*)d_in[16];
  const float* wih_b1 = (const float*)d_in[17];
  const float* whh_b1 = (const float*)d_in[18];
  const float* bih_b1 = (const float*)d_in[19];
  const float* bhh_b1 = (const float*)d_in[20];
  const float* wih_b2 = (const float*)d_in[21];
  const float* whh_b2 = (const float*)d_in[22];
  const float* bih_b2 = (const float*)d_in[23];
  const float* bhh_b2 = (const float*)d_in[24];
  float* out = (float*)d_out;

  lstm_pipe_k<<<BB, 384, 0, stream>>>(
      x,
      wih_a0, whh_a0, bih_a0, bhh_a0,
      wih_a1, whh_a1, bih_a1, bhh_a1,
      wih_a2, whh_a2, bih_a2, bhh_a2,
      wih_b0, whh_b0, bih_b0, bhh_b0,
      wih_b1, whh_b1, bih_b1, bhh_b1,
      wih_b2, whh_b2, bih_b2, bhh_b2,
      out);
}

// Round 12
// 338.426 us; speedup vs baseline: 1.2142x; 1.0269x over previous
//
#include <hip/hip_runtime.h>

// AttackLSTM R27 — all matvecs on MFMA + CH=4 (4-window ring slack).
// R26 post-mortem: 283us steady; rec waves still AGPR-park wt[4][32]
// (185 live > 128 arch) -> fdot2 copy tax remains on the critical path;
// and NS/CH=2 windows of slack half-serializes each producer/consumer
// pair (period >= (T_P+T_C)/2). R27: (1) rec matvec -> R22's validated
// MFMA path (A=h via 4x ds_read_b64, B=whh AGPR fragments in the R26
// union, cndmask extract p[g]=acc[4g+(l>>4)][0]); rec arch live ~95 ->
// no parking, no copy tax, 4 b64 LDS reads/step (was 8 b128 + tax).
// (2) CH=4, NS=16 -> slack 4 windows; back edge k>=4 waits k-3; pairs
// decouple to period ~ max(T_stage). (3) proj MFMA verbatim R26 with
// wr=(lane&15)<4. b-chain fdot2 via union wtb. hh HP=72 / pj PP=260
// padding kept. Self-timed prog[6]: w0->w4->w1->w5->w2->w3.
// Verify: WRITE ~0.6MB, MfmaUtil 8-15%, dur 180-230us, absmax=0.

#define BB 256
#define TT 512
#define CH 4
#define NS 16  // ring slots = 4*CH -> 4-window slack
#define NW (TT / CH)
#define HP 72   // padded hh row (halfs): 144B
#define PP 260  // padded pj row (floats): 1040B

typedef _Float16 v2h __attribute__((ext_vector_type(2)));
typedef _Float16 v8h __attribute__((ext_vector_type(8)));
typedef float v4f __attribute__((ext_vector_type(4)));

__device__ __forceinline__ float sig_(float x) {
  return __builtin_amdgcn_rcpf(1.f + __builtin_amdgcn_exp2f(-1.44269504f * x));
}
__device__ __forceinline__ float tanh_(float x) {
  return __builtin_fmaf(2.f, __builtin_amdgcn_rcpf(1.f + __builtin_amdgcn_exp2f(-2.88539008f * x)), -1.f);
}

template <int K>
__device__ __forceinline__ float qb_(float v) {
  return __int_as_float(__builtin_amdgcn_update_dpp(
      0, __float_as_int(v), (K | (K << 2) | (K << 4) | (K << 6)), 0xF, 0xF, true));
}

#if __has_builtin(__builtin_amdgcn_fdot2)
#define FDOT2(acc, a, b) (acc) = __builtin_amdgcn_fdot2((a), (b), (acc), false)
#else
#define FDOT2(acc, a, b) \
  (acc) = __builtin_fmaf((float)(a)[0], (float)(b)[0], \
          __builtin_fmaf((float)(a)[1], (float)(b)[1], (acc)))
#endif
#define KEEPP(a) asm volatile("" : "+v"(a))
#define PIN16(w)                                                            \
  do {                                                                      \
    _Pragma("unroll") for (int _i = 0; _i < 16; ++_i) KEEPP((w)[_i]);       \
  } while (0)

// Spin until prog[i] >= v (acquire), sleeping between polls.
#define WAITP(i, v)                                                           \
  while (__hip_atomic_load(&prog[i], __ATOMIC_ACQUIRE,                        \
                           __HIP_MEMORY_SCOPE_WORKGROUP) < (v)) {             \
    __builtin_amdgcn_s_sleep(1);                                              \
  }
// Publish prog[i] = v after all this wave's data ds_writes retired.
#define POSTP(i, v)                                                           \
  do {                                                                        \
    asm volatile("s_waitcnt lgkmcnt(0)" ::: "memory");                        \
    if (lane == 0)                                                            \
      __hip_atomic_store(&prog[i], (v), __ATOMIC_RELEASE,                     \
                         __HIP_MEMORY_SCOPE_WORKGROUP);                       \
  } while (0)

__device__ __forceinline__ v2h bc2h_(int v) { return __builtin_bit_cast(v2h, v); }

// 64 halfs from LDS as 32 v2h via int4 reads (8x ds_read_b128, broadcast).
__device__ __forceinline__ void load_h64(const _Float16* p, v2h hv[32]) {
  const int4* hp = reinterpret_cast<const int4*>(p);
#pragma unroll
  for (int i = 0; i < 8; ++i) {
    int4 blk = hp[i];
    hv[4 * i + 0] = bc2h_(blk.x);
    hv[4 * i + 1] = bc2h_(blk.y);
    hv[4 * i + 2] = bc2h_(blk.z);
    hv[4 * i + 3] = bc2h_(blk.w);
  }
}

// fp32 row of 64 -> two 16-v2h halves (b-chain).
__device__ __forceinline__ void load_row_pair(const float* src, v2h* lo, v2h* hi) {
  const float4* p = reinterpret_cast<const float4*>(src);
#pragma unroll
  for (int i = 0; i < 8; ++i) {
    float4 v = p[i];
    lo[2 * i]     = v2h{(_Float16)v.x, (_Float16)v.y};
    lo[2 * i + 1] = v2h{(_Float16)v.z, (_Float16)v.w};
  }
#pragma unroll
  for (int i = 0; i < 8; ++i) {
    float4 v = p[8 + i];
    hi[2 * i]     = v2h{(_Float16)v.x, (_Float16)v.y};
    hi[2 * i + 1] = v2h{(_Float16)v.z, (_Float16)v.w};
  }
}

// W-fragment for tile t, K-chunk kc of W[256x64] row-major f32 (validated).
__device__ __forceinline__ v8h ldbfrag_(const float* W, int t, int kc, int lane) {
  const int row = 16 * t + (lane & 15);
  const float* p = W + row * 64 + 32 * kc + 4 * (lane >> 4);
  float4 fa = *reinterpret_cast<const float4*>(p);
  float4 fb = *reinterpret_cast<const float4*>(p + 16);
  return v8h{(_Float16)fa.x, (_Float16)fa.y, (_Float16)fa.z, (_Float16)fa.w,
             (_Float16)fb.x, (_Float16)fb.y, (_Float16)fb.z, (_Float16)fb.w};
}

__global__ __attribute__((amdgpu_flat_work_group_size(384, 384),
                          amdgpu_waves_per_eu(2, 2)))
void lstm_pipe_k(
    const float* __restrict__ x,
    const float* __restrict__ wih_a0, const float* __restrict__ whh_a0,
    const float* __restrict__ bih_a0, const float* __restrict__ bhh_a0,
    const float* __restrict__ wih_a1, const float* __restrict__ whh_a1,
    const float* __restrict__ bih_a1, const float* __restrict__ bhh_a1,
    const float* __restrict__ wih_a2, const float* __restrict__ whh_a2,
    const float* __restrict__ bih_a2, const float* __restrict__ bhh_a2,
    const float* __restrict__ wih_b0, const float* __restrict__ whh_b0,
    const float* __restrict__ bih_b0, const float* __restrict__ bhh_b0,
    const float* __restrict__ wih_b1, const float* __restrict__ whh_b1,
    const float* __restrict__ bih_b1, const float* __restrict__ bhh_b1,
    const float* __restrict__ wih_b2, const float* __restrict__ whh_b2,
    const float* __restrict__ bih_b2, const float* __restrict__ bhh_b2,
    float* __restrict__ out)  // [B,T]
{
  const int b = blockIdx.x;
  const int tid = threadIdx.x;
  const int wave = tid >> 6;
  const int lane = tid & 63;

  __shared__ __align__(16) _Float16 hh[3][NS][HP];  // h rings (padded rows)
  __shared__ __align__(16) float pj[2][NS][PP];     // proj rings (padded rows)
  __shared__ float xs[TT];
  __shared__ int prog[6];                           // per-wave windows done

  for (int i = tid; i < TT; i += 384) xs[i] = x[(size_t)b * TT + i];
  for (int i = tid; i < 3 * NS * HP / 2; i += 384) reinterpret_cast<int*>(hh)[i] = 0;
  if (tid < 6) prog[tid] = 0;

  // Register overlay (R26-proven): rec+proj waves use u.bfr (AGPR), b uses u.wtb.
  union UW {
    v8h bfr[16][2];
    v2h wtb[2][16];
  } u;

  float bias[4] = {0.f, 0.f, 0.f, 0.f};
  float wi0_[4] = {0.f, 0.f, 0.f, 0.f};
  float whb0[4] = {}, wi1b[4] = {}, wh1b[4] = {}, bb1[4] = {},
        wi2b[4] = {}, wh2b[4] = {}, bb2[4] = {};

  if (wave == 0) {  // a0 rec: B = whh_a0 fragments
#pragma unroll
    for (int t = 0; t < 16; ++t) {
      u.bfr[t][0] = ldbfrag_(whh_a0, t, 0, lane);
      u.bfr[t][1] = ldbfrag_(whh_a0, t, 1, lane);
    }
#pragma unroll
    for (int q = 0; q < 4; ++q) {
      const int row = q * 64 + lane;
      bias[q] = bih_a0[row] + bhh_a0[row];
      wi0_[q] = wih_a0[row];
    }
  } else if (wave == 1) {  // a1 rec
#pragma unroll
    for (int t = 0; t < 16; ++t) {
      u.bfr[t][0] = ldbfrag_(whh_a1, t, 0, lane);
      u.bfr[t][1] = ldbfrag_(whh_a1, t, 1, lane);
    }
#pragma unroll
    for (int q = 0; q < 4; ++q) bias[q] = bih_a1[q * 64 + lane] + bhh_a1[q * 64 + lane];
  } else if (wave == 2) {  // a2 rec
#pragma unroll
    for (int t = 0; t < 16; ++t) {
      u.bfr[t][0] = ldbfrag_(whh_a2, t, 0, lane);
      u.bfr[t][1] = ldbfrag_(whh_a2, t, 1, lane);
    }
#pragma unroll
    for (int q = 0; q < 4; ++q) bias[q] = bih_a2[q * 64 + lane] + bhh_a2[q * 64 + lane];
  } else if (wave == 3) {  // b-chain
    const int q = lane & 3;
    load_row_pair(wih_b0 + q * 64, u.wtb[0], u.wtb[1]);
    bias[0] = bih_b0[q] + bhh_b0[q];
#pragma unroll
    for (int k = 0; k < 4; ++k) {
      whb0[k] = whh_b0[k];
      wi1b[k] = wih_b1[k]; wh1b[k] = whh_b1[k]; bb1[k] = bih_b1[k] + bhh_b1[k];
      wi2b[k] = wih_b2[k]; wh2b[k] = whh_b2[k]; bb2[k] = bih_b2[k] + bhh_b2[k];
    }
    PIN16(u.wtb[0]); PIN16(u.wtb[1]);
  } else if (wave == 4) {  // a1 proj MFMA: W = wih_a1
#pragma unroll
    for (int t = 0; t < 16; ++t) {
      u.bfr[t][0] = ldbfrag_(wih_a1, t, 0, lane);
      u.bfr[t][1] = ldbfrag_(wih_a1, t, 1, lane);
    }
  } else {                 // wave 5: a2 proj MFMA: W = wih_a2
#pragma unroll
    for (int t = 0; t < 16; ++t) {
      u.bfr[t][0] = ldbfrag_(wih_a2, t, 0, lane);
      u.bfr[t][1] = ldbfrag_(wih_a2, t, 1, lane);
    }
  }
  __syncthreads();

  float c = 0.f;
  float h0b = 0.f, c0b = 0.f, h1b = 0.f, c1b = 0.f, h2b = 0.f, c2b = 0.f;
  const int q4 = lane >> 4;
  const bool s0 = q4 & 1, s1 = q4 & 2;
  const v4f z = {0.f, 0.f, 0.f, 0.f};

  if (wave == 0) {  // a0 rec -> hh[0]; consumer w4
    __builtin_amdgcn_s_setprio(1);
    for (int k = 0; k < NW; ++k) {
      if (k >= 4) { WAITP(4, k - 3); }
      const int t0 = k * CH;
      for (int s = 0; s < CH; ++s) {
        const int t = t0 + s;
        const char* hp = (const char*)(&hh[0][(t + NS - 1) & (NS - 1)][0]) + 8 * q4;
        int2 r00 = *(const int2*)(hp);
        int2 r01 = *(const int2*)(hp + 32);
        int2 r10 = *(const int2*)(hp + 64);
        int2 r11 = *(const int2*)(hp + 96);
        v8h A0 = __builtin_bit_cast(v8h, int4{r00.x, r00.y, r01.x, r01.y});
        v8h A1 = __builtin_bit_cast(v8h, int4{r10.x, r10.y, r11.x, r11.y});
        v4f acc[16];
#pragma unroll
        for (int tl = 0; tl < 16; ++tl) {
          v4f d = __builtin_amdgcn_mfma_f32_16x16x32_f16(A0, u.bfr[tl][0], z, 0, 0, 0);
          acc[tl] = __builtin_amdgcn_mfma_f32_16x16x32_f16(A1, u.bfr[tl][1], d, 0, 0, 0);
        }
        float p[4];
#pragma unroll
        for (int g = 0; g < 4; ++g) {
          float v01 = s0 ? acc[4 * g + 1][0] : acc[4 * g + 0][0];
          float v23 = s0 ? acc[4 * g + 3][0] : acc[4 * g + 2][0];
          p[g] = s1 ? v23 : v01;
        }
        const float xv = xs[t];
        float p0 = __builtin_fmaf(wi0_[0], xv, p[0] + bias[0]);
        float p1 = __builtin_fmaf(wi0_[1], xv, p[1] + bias[1]);
        float p2 = __builtin_fmaf(wi0_[2], xv, p[2] + bias[2]);
        float p3 = __builtin_fmaf(wi0_[3], xv, p[3] + bias[3]);
        float gi = sig_(p0), gf = sig_(p1), gg = tanh_(p2), go = sig_(p3);
        c = __builtin_fmaf(gf, c, gi * gg);
        hh[0][t & (NS - 1)][lane] = (_Float16)(go * tanh_(c));
      }
      POSTP(0, k + 1);
    }
    __builtin_amdgcn_s_setprio(0);
  } else if (wave == 1) {  // a1 rec: reads pj[0]; -> hh[1]; consumer w5
    __builtin_amdgcn_s_setprio(1);
    for (int k = 0; k < NW; ++k) {
      WAITP(4, k + 1);
      if (k >= 4) { WAITP(5, k - 3); }
      const int t0 = k * CH;
      for (int s = 0; s < CH; ++s) {
        const int t = t0 + s;
        const char* hp = (const char*)(&hh[1][(t + NS - 1) & (NS - 1)][0]) + 8 * q4;
        int2 r00 = *(const int2*)(hp);
        int2 r01 = *(const int2*)(hp + 32);
        int2 r10 = *(const int2*)(hp + 64);
        int2 r11 = *(const int2*)(hp + 96);
        v8h A0 = __builtin_bit_cast(v8h, int4{r00.x, r00.y, r01.x, r01.y});
        v8h A1 = __builtin_bit_cast(v8h, int4{r10.x, r10.y, r11.x, r11.y});
        float4 pr = *reinterpret_cast<const float4*>(&pj[0][t & (NS - 1)][lane * 4]);
        v4f acc[16];
#pragma unroll
        for (int tl = 0; tl < 16; ++tl) {
          v4f d = __builtin_amdgcn_mfma_f32_16x16x32_f16(A0, u.bfr[tl][0], z, 0, 0, 0);
          acc[tl] = __builtin_amdgcn_mfma_f32_16x16x32_f16(A1, u.bfr[tl][1], d, 0, 0, 0);
        }
        float p[4];
#pragma unroll
        for (int g = 0; g < 4; ++g) {
          float v01 = s0 ? acc[4 * g + 1][0] : acc[4 * g + 0][0];
          float v23 = s0 ? acc[4 * g + 3][0] : acc[4 * g + 2][0];
          p[g] = s1 ? v23 : v01;
        }
        float p0 = p[0] + bias[0] + pr.x;
        float p1 = p[1] + bias[1] + pr.y;
        float p2 = p[2] + bias[2] + pr.z;
        float p3 = p[3] + bias[3] + pr.w;
        float gi = sig_(p0), gf = sig_(p1), gg = tanh_(p2), go = sig_(p3);
        c = __builtin_fmaf(gf, c, gi * gg);
        hh[1][t & (NS - 1)][lane] = (_Float16)(go * tanh_(c));
      }
      POSTP(1, k + 1);
    }
    __builtin_amdgcn_s_setprio(0);
  } else if (wave == 2) {  // a2 rec: reads pj[1]; -> hh[2]; consumer w3
    __builtin_amdgcn_s_setprio(1);
    for (int k = 0; k < NW; ++k) {
      WAITP(5, k + 1);
      if (k >= 4) { WAITP(3, k - 3); }
      const int t0 = k * CH;
      for (int s = 0; s < CH; ++s) {
        const int t = t0 + s;
        const char* hp = (const char*)(&hh[2][(t + NS - 1) & (NS - 1)][0]) + 8 * q4;
        int2 r00 = *(const int2*)(hp);
        int2 r01 = *(const int2*)(hp + 32);
        int2 r10 = *(const int2*)(hp + 64);
        int2 r11 = *(const int2*)(hp + 96);
        v8h A0 = __builtin_bit_cast(v8h, int4{r00.x, r00.y, r01.x, r01.y});
        v8h A1 = __builtin_bit_cast(v8h, int4{r10.x, r10.y, r11.x, r11.y});
        float4 pr = *reinterpret_cast<const float4*>(&pj[1][t & (NS - 1)][lane * 4]);
        v4f acc[16];
#pragma unroll
        for (int tl = 0; tl < 16; ++tl) {
          v4f d = __builtin_amdgcn_mfma_f32_16x16x32_f16(A0, u.bfr[tl][0], z, 0, 0, 0);
          acc[tl] = __builtin_amdgcn_mfma_f32_16x16x32_f16(A1, u.bfr[tl][1], d, 0, 0, 0);
        }
        float p[4];
#pragma unroll
        for (int g = 0; g < 4; ++g) {
          float v01 = s0 ? acc[4 * g + 1][0] : acc[4 * g + 0][0];
          float v23 = s0 ? acc[4 * g + 3][0] : acc[4 * g + 2][0];
          p[g] = s1 ? v23 : v01;
        }
        float p0 = p[0] + bias[0] + pr.x;
        float p1 = p[1] + bias[1] + pr.y;
        float p2 = p[2] + bias[2] + pr.z;
        float p3 = p[3] + bias[3] + pr.w;
        float gi = sig_(p0), gf = sig_(p1), gg = tanh_(p2), go = sig_(p3);
        c = __builtin_fmaf(gf, c, gi * gg);
        hh[2][t & (NS - 1)][lane] = (_Float16)(go * tanh_(c));
      }
      POSTP(2, k + 1);
    }
    __builtin_amdgcn_s_setprio(0);
  } else if (wave == 3) {  // b-chain: reads hh[2]
    for (int k = 0; k < NW; ++k) {
      WAITP(2, k + 1);
      const int t0 = k * CH;
      for (int s = 0; s < CH; ++s) {
        const int t = t0 + s;
        v2h hv[32];
        load_h64(&hh[2][t & (NS - 1)][0], hv);
        float pga = bias[0], pgb = 0.f;
#pragma unroll
        for (int j = 0; j < 16; ++j) {
          FDOT2(pga, u.wtb[0][j], hv[j]);
          FDOT2(pgb, u.wtb[1][j], hv[16 + j]);
        }
        float pg = pga + pgb;
        float p_i = qb_<0>(pg), p_f = qb_<1>(pg), p_g = qb_<2>(pg), p_o = qb_<3>(pg);
        float i0 = sig_(__builtin_fmaf(whb0[0], h0b, p_i));
        float f0 = sig_(__builtin_fmaf(whb0[1], h0b, p_f));
        float g0 = tanh_(__builtin_fmaf(whb0[2], h0b, p_g));
        float o0 = sig_(__builtin_fmaf(whb0[3], h0b, p_o));
        c0b = __builtin_fmaf(f0, c0b, i0 * g0);
        h0b = o0 * tanh_(c0b);
        float i1 = sig_(bb1[0] + __builtin_fmaf(wi1b[0], h0b, wh1b[0] * h1b));
        float f1 = sig_(bb1[1] + __builtin_fmaf(wi1b[1], h0b, wh1b[1] * h1b));
        float g1 = tanh_(bb1[2] + __builtin_fmaf(wi1b[2], h0b, wh1b[2] * h1b));
        float o1 = sig_(bb1[3] + __builtin_fmaf(wi1b[3], h0b, wh1b[3] * h1b));
        c1b = __builtin_fmaf(f1, c1b, i1 * g1);
        h1b = o1 * tanh_(c1b);
        float i2 = sig_(bb2[0] + __builtin_fmaf(wi2b[0], h1b, wh2b[0] * h2b));
        float f2 = sig_(bb2[1] + __builtin_fmaf(wi2b[1], h1b, wh2b[1] * h2b));
        float g2 = tanh_(bb2[2] + __builtin_fmaf(wi2b[2], h1b, wh2b[2] * h2b));
        float o2 = sig_(bb2[3] + __builtin_fmaf(wi2b[3], h1b, wh2b[3] * h2b));
        c2b = __builtin_fmaf(f2, c2b, i2 * g2);
        h2b = o2 * tanh_(c2b);
        if (lane == 0) out[(size_t)b * TT + t] = h2b;
      }
      POSTP(3, k + 1);
    }
  } else if (wave == 4) {  // a1 proj MFMA: hh[0] window k -> pj[0] window k
    for (int k = 0; k < NW; ++k) {
      WAITP(0, k + 1);
      if (k >= 4) { WAITP(1, k - 3); }
      const int t0 = k * CH;
      const int slotb = (t0 + (lane & 15)) & (NS - 1);
      const char* hp = (const char*)(&hh[0][slotb][0]) + 8 * q4;
      int2 r00 = *(const int2*)(hp);
      int2 r01 = *(const int2*)(hp + 32);
      int2 r10 = *(const int2*)(hp + 64);
      int2 r11 = *(const int2*)(hp + 96);
      v8h Bf0 = __builtin_bit_cast(v8h, int4{r00.x, r00.y, r01.x, r01.y});
      v8h Bf1 = __builtin_bit_cast(v8h, int4{r10.x, r10.y, r11.x, r11.y});
      float* pbase = &pj[0][slotb][0] + 16 * q4;
      const bool wr = (lane & 15) < CH;  // cols >= CH garbage (other windows)
#pragma unroll
      for (int tl = 0; tl < 16; ++tl) {
        v4f acc = __builtin_amdgcn_mfma_f32_16x16x32_f16(u.bfr[tl][0], Bf0, z, 0, 0, 0);
        acc = __builtin_amdgcn_mfma_f32_16x16x32_f16(u.bfr[tl][1], Bf1, acc, 0, 0, 0);
        if (wr) {
          const int o = 64 * (tl & 3) + (tl >> 2);
          pbase[o] = acc[0]; pbase[o + 4] = acc[1];
          pbase[o + 8] = acc[2]; pbase[o + 12] = acc[3];
        }
        __builtin_amdgcn_sched_barrier(0);
      }
      POSTP(4, k + 1);
    }
  } else {                 // wave 5: a2 proj MFMA: hh[1] window k -> pj[1]
    for (int k = 0; k < NW; ++k) {
      WAITP(1, k + 1);
      if (k >= 4) { WAITP(2, k - 3); }
      const int t0 = k * CH;
      const int slotb = (t0 + (lane & 15)) & (NS - 1);
      const char* hp = (const char*)(&hh[1][slotb][0]) + 8 * q4;
      int2 r00 = *(const int2*)(hp);
      int2 r01 = *(const int2*)(hp + 32);
      int2 r10 = *(const int2*)(hp + 64);
      int2 r11 = *(const int2*)(hp + 96);
      v8h Bf0 = __builtin_bit_cast(v8h, int4{r00.x, r00.y, r01.x, r01.y});
      v8h Bf1 = __builtin_bit_cast(v8h, int4{r10.x, r10.y, r11.x, r11.y});
      float* pbase = &pj[1][slotb][0] + 16 * q4;
      const bool wr = (lane & 15) < CH;
#pragma unroll
      for (int tl = 0; tl < 16; ++tl) {
        v4f acc = __builtin_amdgcn_mfma_f32_16x16x32_f16(u.bfr[tl][0], Bf0, z, 0, 0, 0);
        acc = __builtin_amdgcn_mfma_f32_16x16x32_f16(u.bfr[tl][1], Bf1, acc, 0, 0, 0);
        if (wr) {
          const int o = 64 * (tl & 3) + (tl >> 2);
          pbase[o] = acc[0]; pbase[o + 4] = acc[1];
          pbase[o + 8] = acc[2]; pbase[o + 12] = acc[3];
        }
        __builtin_amdgcn_sched_barrier(0);
      }
      POSTP(5, k + 1);
    }
  }
}

extern "C" void kernel_launch(void* const* d_in, const int* in_sizes, int n_in,
                              void* d_out, int out_size, void* d_ws, size_t ws_size,
                              hipStream_t stream) {
  const float* x      = (const float*)d_in[0];
  const float* wih_a0 = (const float*)d_in[1];
  const float* whh_a0 = (const float*)d_in[2];
  const float* bih_a0 = (const float*)d_in[3];
  const float* bhh_a0 = (const float*)d_in[4];
  const float* wih_a1 = (const float*)d_in[5];
  const float* whh_a1 = (const float*)d_in[6];
  const float* bih_a1 = (const float*)d_in[7];
  const float* bhh_a1 = (const float*)d_in[8];
  const float* wih_a2 = (const float*)d_in[9];
  const float* whh_a2 = (const float*)d_in[10];
  const float* bih_a2 = (const float*)d_in[11];
  const float* bhh_a2 = (const float*)d_in[12];
  const float* wih_b0 = (const float*)d_in[13];
  const float* whh_b0 = (const float*)d_in[14];
  const float* bih_b0 = (const float*)d_in[15];
  const float* bhh_b0 = (const float*)d_in[16];
  const float* wih_b1 = (const float*)d_in[17];
  const float* whh_b1 = (const float*)d_in[18];
  const float* bih_b1 = (const float*)d_in[19];
  const float* bhh_b1 = (const float*)d_in[20];
  const float* wih_b2 = (const float*)d_in[21];
  const float* whh_b2 = (const float*)d_in[22];
  const float* bih_b2 = (const float*)d_in[23];
  const float* bhh_b2 = (const float*)d_in[24];
  float* out = (float*)d_out;

  lstm_pipe_k<<<BB, 384, 0, stream>>>(
      x,
      wih_a0, whh_a0, bih_a0, bhh_a0,
      wih_a1, whh_a1, bih_a1, bhh_a1,
      wih_a2, whh_a2, bih_a2, bhh_a2,
      wih_b0, whh_b0, bih_b0, bhh_b0,
      wih_b1, whh_b1, bih_b1, bhh_b1,
      wih_b2, whh_b2, bih_b2, bhh_b2,
      out);
}